// Round 2
// baseline (537.733 us; speedup 1.0000x reference)
//
#include <hip/hip_runtime.h>
#include <hip/hip_bf16.h>
#include <math.h>

#define Nn 10000
#define Ee 160000
#define ET 170000   // Ee + Nn (self loops)
#define LL 6

typedef short v8s __attribute__((ext_vector_type(8)));
typedef float v4f __attribute__((ext_vector_type(4)));
typedef float v2f __attribute__((ext_vector_type(2)));

__device__ __forceinline__ unsigned short f2bf(float v) {
    unsigned int b = __float_as_uint(v);
    b += 0x7fffu + ((b >> 16) & 1u);   // RNE
    return (unsigned short)(b >> 16);
}
__device__ __forceinline__ float bflo(unsigned int u) { return __uint_as_float(u << 16); }
__device__ __forceinline__ float bfhi(unsigned int u) { return __uint_as_float(u & 0xffff0000u); }

// ---------------- node embedding: h = x @ node_w + node_b (fp32 + bf16 mirror) ----------------
__global__ void k_node_embed(const float* __restrict__ x, const float* __restrict__ nw,
                             const float* __restrict__ nb, float* __restrict__ h,
                             unsigned short* __restrict__ hb) {
    int idx = blockIdx.x * 256 + threadIdx.x;
    if (idx >= Nn * 128) return;
    int n = idx >> 7, c = idx & 127;
    const float* xr = x + (size_t)n * 8;
    float acc = nb[c];
#pragma unroll
    for (int k = 0; k < 8; k++) acc += xr[k] * nw[k * 128 + c];
    h[idx] = acc;
    hb[idx] = f2bf(acc);
}

// ---------------- small precompute: E1[128][8] = {M1[0..3][k], d1[k], 0,0,0} ----------------
__global__ void k_small(const float* __restrict__ vnfc, const float* __restrict__ vw,
                        const float* __restrict__ vb, const float* __restrict__ eab,
                        const float* __restrict__ a1w, const float* __restrict__ a1b,
                        const float* __restrict__ eaw, float* __restrict__ E1) {
    __shared__ float vr[128];
    __shared__ float sM1[512];
    __shared__ float sd1[128];
    int t = threadIdx.x;   // 512
    if (t < 128) {
        float a = vb[t];
#pragma unroll
        for (int k = 0; k < 6; k++) a += vnfc[k] * vw[k * 128 + t];
        vr[t] = a;
    }
    __syncthreads();
    if (t < 128) {
        float a = a1b[t];
        for (int k = 0; k < 128; k++) a += eab[k] * a1w[k * 128 + t];
        for (int k = 0; k < 128; k++) a += vr[k] * a1w[(128 + k) * 128 + t];
        sd1[t] = a;
    }
    {
        int r = t >> 7, j = t & 127;
        float a = 0.f;
        for (int k = 0; k < 128; k++) a += eaw[r * 128 + k] * a1w[k * 128 + j];
        sM1[r * 128 + j] = a;
    }
    __syncthreads();
    if (t < 128) {
        E1[t * 8 + 0] = sM1[t];
        E1[t * 8 + 1] = sM1[128 + t];
        E1[t * 8 + 2] = sM1[256 + t];
        E1[t * 8 + 3] = sM1[384 + t];
        E1[t * 8 + 4] = sd1[t];
        E1[t * 8 + 5] = 0.f; E1[t * 8 + 6] = 0.f; E1[t * 8 + 7] = 0.f;
    }
}

// ---------------- B matrices: Bs/Bd/Be [L][128][4] ----------------
__global__ void k_bmat(const float* __restrict__ glw, const float* __restrict__ gas,
                       const float* __restrict__ gad, const float* __restrict__ glew,
                       const float* __restrict__ gae, float* __restrict__ Bs,
                       float* __restrict__ Bd, float* __restrict__ Be) {
    int idx = blockIdx.x * 256 + threadIdx.x;
    if (idx >= LL * 128 * 4) return;
    int hh = idx & 3, k = (idx >> 2) & 127, l = idx >> 9;
    const float* lwp = glw  + (size_t)l * 65536 + k * 512 + hh * 128;
    const float* lep = glew + (size_t)l * 65536 + k * 512 + hh * 128;
    const float* sp = gas + l * 512 + hh * 128;
    const float* dp = gad + l * 512 + hh * 128;
    const float* ep = gae + l * 512 + hh * 128;
    float s1 = 0, s2 = 0, s3 = 0;
    for (int c = 0; c < 128; c++) {
        float lv = lwp[c];
        s1 += lv * sp[c];
        s2 += lv * dp[c];
        s3 += lep[c] * ep[c];
    }
    Bs[idx] = s1; Bd[idx] = s2; Be[idx] = s3;
}

// ---- WsumT[l][c][kk] bf16 = 0.25 * lw_l[kk&127][ (kk>>7)*128 + c ]  (B^T for k_post) ----
__global__ void k_wsum(const float* __restrict__ glw, unsigned short* __restrict__ WsumT) {
    int idx = blockIdx.x * 256 + threadIdx.x;
    if (idx >= LL * 128 * 512) return;
    int kk = idx & 511;
    int c = (idx >> 9) & 127;
    int l = idx >> 16;
    float v = 0.25f * glw[(size_t)l * 65536 + (size_t)(kk & 127) * 512 + (kk >> 7) * 128 + c];
    WsumT[(size_t)l * 65536 + (size_t)c * 512 + kk] = f2bf(v);
}

// ---- w2 (att2_w [128][64]) converted to bf16 in MFMA B-fragment order ----
__global__ void k_w2b(const float* __restrict__ a2w, unsigned short* __restrict__ w2bf) {
    int idx = blockIdx.x * 256 + threadIdx.x;
    if (idx >= 8192) return;
    int j = idx & 7, lane = (idx >> 3) & 63, nt = (idx >> 9) & 3, ks = idx >> 11;
    int k = ks * 32 + ((lane >> 4) << 3) + j;
    int n = nt * 16 + (lane & 15);
    w2bf[idx] = f2bf(a2w[k * 64 + n]);
}

// ---------------- PB[4][24], cB[24]: fold ea_proj through Be ----------------
__global__ void k_pb(const float* __restrict__ eaw, const float* __restrict__ eab,
                     const float* __restrict__ Be, float* __restrict__ PB,
                     float* __restrict__ cB) {
    int t = threadIdx.x;
    if (t >= 24) return;
    int l = t >> 2, hh = t & 3;
    const float* bp = Be + l * 512 + hh;
    float s0 = 0, s1 = 0, s2 = 0, s3 = 0, sc = 0;
    for (int k = 0; k < 128; k++) {
        float bv = bp[k * 4];
        s0 += eaw[0 * 128 + k] * bv;
        s1 += eaw[1 * 128 + k] * bv;
        s2 += eaw[2 * 128 + k] * bv;
        s3 += eaw[3 * 128 + k] * bv;
        sc += eab[k] * bv;
    }
    PB[0 * 24 + t] = s0; PB[1 * 24 + t] = s1;
    PB[2 * 24 + t] = s2; PB[3 * 24 + t] = s3;
    cB[t] = sc;
}

// ---- edge gate MLP, MFMA version: 256 edges/block, 4 waves, 64 MFMA/wave ----
__global__ __launch_bounds__(256, 2) void k_edge(
    const float* __restrict__ ea, const float* __restrict__ E1,
    const unsigned short* __restrict__ w2bf,
    const float* __restrict__ a2b, const float* __restrict__ a3w,
    const float* __restrict__ a3b,
    const float* __restrict__ PB, const float* __restrict__ cB,
    float* __restrict__ aleT, float* __restrict__ gsum) {
    __shared__ float4 sM[128];     // swizzled: row k stored at k ^ ((k>>3)&3)
    __shared__ float sD[128];
    __shared__ float4 sevs[256];
    __shared__ float gsh[256];
    __shared__ float sgsum[5];
    int t = threadIdx.x;
    int lane = t & 63;
    int wid = t >> 6;
    int c = lane & 15, q = lane >> 4;
    int eb0 = blockIdx.x * 256;

    sevs[t] = *(const float4*)(ea + (size_t)(eb0 + t) * 4);
    if (t < 128) {
        int slot = t ^ ((t >> 3) & 3);
        sM[slot] = *(const float4*)(E1 + t * 8);
        sD[t] = E1[t * 8 + 4];
    }
    if (t < 5) sgsum[t] = 0.f;
    __syncthreads();

    float4 ev4[4];
#pragma unroll
    for (int mt = 0; mt < 4; mt++) ev4[mt] = sevs[(wid * 4 + mt) * 16 + c];

    // ---- layer 1: hidden1 -> bf16 A-fragments av[mt][ks] ----
    v8s av[4][4];
#pragma unroll
    for (int ks = 0; ks < 4; ks++) {
        float4 mr[8]; float dr[8];
#pragma unroll
        for (int j = 0; j < 8; j++) {
            int k = ks * 32 + q * 8 + j;
            mr[j] = sM[k ^ q];
            dr[j] = sD[k];
        }
#pragma unroll
        for (int mt = 0; mt < 4; mt++) {
            float4 ev = ev4[mt];
            v8s a;
#pragma unroll
            for (int j = 0; j < 8; j++) {
                float xv = fmaxf(dr[j] + ev.x * mr[j].x + ev.y * mr[j].y
                                       + ev.z * mr[j].z + ev.w * mr[j].w, 0.f);
                a[j] = (short)f2bf(xv);
            }
            av[mt][ks] = a;
        }
    }

    // ---- layer 2: MFMA, bias folded into C-init ----
    v4f acc[4][4];   // [mt][nt]
#pragma unroll
    for (int nt = 0; nt < 4; nt++) {
        float bb = a2b[nt * 16 + c];
#pragma unroll
        for (int mt = 0; mt < 4; mt++) acc[mt][nt] = (v4f){bb, bb, bb, bb};
    }
#pragma unroll
    for (int nt = 0; nt < 4; nt++) {
#pragma unroll
        for (int ks = 0; ks < 4; ks++) {
            v8s b = *(const v8s*)(w2bf + ((size_t)(ks * 4 + nt) * 64 + lane) * 8);
#pragma unroll
            for (int mt = 0; mt < 4; mt++)
                acc[mt][nt] = __builtin_amdgcn_mfma_f32_16x16x32_bf16(av[mt][ks], b, acc[mt][nt], 0, 0, 0);
        }
    }

    // ---- layer 3 + sigmoid ----
    float a3r[4];
#pragma unroll
    for (int nt = 0; nt < 4; nt++) a3r[nt] = a3w[nt * 16 + c];
    float a3b0 = a3b[0];
#pragma unroll
    for (int mt = 0; mt < 4; mt++) {
#pragma unroll
        for (int r = 0; r < 4; r++) {
            float s = 0.f;
#pragma unroll
            for (int nt = 0; nt < 4; nt++) s += fmaxf(acc[mt][nt][r], 0.f) * a3r[nt];
            s += __shfl_xor(s, 1); s += __shfl_xor(s, 2);
            s += __shfl_xor(s, 4); s += __shfl_xor(s, 8);
            if (c == 0) gsh[(wid * 4 + mt) * 16 + q * 4 + r] = 1.f / (1.f + __expf(-(s + a3b0)));
        }
    }
    __syncthreads();

    // ---- per-edge epilogue ----
    float g = gsh[t];
    float4 evv = sevs[t];
    float v0 = g, v1 = g * evv.x, v2 = g * evv.y, v3 = g * evv.z, v4 = g * evv.w;
#pragma unroll
    for (int d = 32; d > 0; d >>= 1) {
        v0 += __shfl_down(v0, d); v1 += __shfl_down(v1, d); v2 += __shfl_down(v2, d);
        v3 += __shfl_down(v3, d); v4 += __shfl_down(v4, d);
    }
    if (lane == 0) {
        atomicAdd(&sgsum[0], v0); atomicAdd(&sgsum[1], v1); atomicAdd(&sgsum[2], v2);
        atomicAdd(&sgsum[3], v3); atomicAdd(&sgsum[4], v4);
    }
    __syncthreads();
    if (t < 5) atomicAdd(&gsum[t], sgsum[t]);
#pragma unroll
    for (int i4 = 0; i4 < 6; i4++) {
        float4 cc = *(const float4*)(cB + i4 * 4);
        float4 p0 = *(const float4*)(PB + 0 * 24 + i4 * 4);
        float4 p1 = *(const float4*)(PB + 1 * 24 + i4 * 4);
        float4 p2 = *(const float4*)(PB + 2 * 24 + i4 * 4);
        float4 p3 = *(const float4*)(PB + 3 * 24 + i4 * 4);
        float4 o;
        o.x = g * (cc.x + evv.x * p0.x + evv.y * p1.x + evv.z * p2.x + evv.w * p3.x);
        o.y = g * (cc.y + evv.x * p0.y + evv.y * p1.y + evv.z * p2.y + evv.w * p3.y);
        o.z = g * (cc.z + evv.x * p0.z + evv.y * p1.z + evv.z * p2.z + evv.w * p3.z);
        o.w = g * (cc.w + evv.x * p0.w + evv.y * p1.w + evv.z * p2.w + evv.w * p3.w);
        *(float4*)(aleT + (size_t)i4 * Ee * 4 + (size_t)(eb0 + t) * 4) = o;
    }
}

// ---------------- loop-edge al_e from G,S sums ----------------
__global__ void k_lale(const float* __restrict__ gsum, const float* __restrict__ PB,
                       const float* __restrict__ cB, float* __restrict__ lale) {
    int t = threadIdx.x;
    if (t >= 24) return;
    float s = gsum[0] * cB[t] + gsum[1] * PB[t] + gsum[2] * PB[24 + t]
            + gsum[3] * PB[48 + t] + gsum[4] * PB[72 + t];
    lale[t] = s * (1.0f / Ee);
}

// ---------------- counting sort by dst: hist / scan / scatter ----------------
__global__ void k_hist(const int* __restrict__ ei, int* __restrict__ hist) {
    int i = blockIdx.x * 256 + threadIdx.x;
    if (i >= ET) return;
    int d = (i < Ee) ? ei[Ee + i] : (i - Ee);
    atomicAdd(&hist[d], 1);
}

__global__ __launch_bounds__(1024) void k_scan(const int* __restrict__ hist,
                                               int* __restrict__ seg, int* __restrict__ pos) {
    __shared__ int wsums[16];
    __shared__ int carry_s;
    int t = threadIdx.x;
    int lane = t & 63, wid = t >> 6;
    if (t == 0) { carry_s = 0; seg[0] = 0; }
    __syncthreads();
    for (int base = 0; base < Nn; base += 1024) {
        int idx = base + t;
        int v = (idx < Nn) ? hist[idx] : 0;
        int sc = v;
#pragma unroll
        for (int d = 1; d < 64; d <<= 1) {
            int up = __shfl_up(sc, d);
            if (lane >= d) sc += up;
        }
        if (lane == 63) wsums[wid] = sc;
        __syncthreads();
        if (wid == 0) {
            int wv = (lane < 16) ? wsums[lane] : 0;
            int wsc = wv;
#pragma unroll
            for (int d = 1; d < 16; d <<= 1) {
                int up = __shfl_up(wsc, d);
                if (lane >= d) wsc += up;
            }
            if (lane < 16) wsums[lane] = wsc - wv;
        }
        __syncthreads();
        int carry = carry_s;
        int inc = sc + wsums[wid] + carry;
        if (idx < Nn) { seg[idx + 1] = inc; pos[idx] = inc - v; }
        __syncthreads();
        if (t == 1023) carry_s = inc;
        __syncthreads();
    }
}

__global__ void k_scatter(const int* __restrict__ ei, int* __restrict__ pos,
                          int2* __restrict__ pse, int* __restrict__ srcv,
                          int* __restrict__ dstv) {
    int i = blockIdx.x * 256 + threadIdx.x;
    if (i >= ET) return;
    int s, d;
    if (i < Ee) { s = ei[i]; d = ei[Ee + i]; } else { s = d = i - Ee; }
    int idx = atomicAdd(&pos[d], 1);
    pse[idx] = make_int2(s, i);
    srcv[idx] = s;
    dstv[idx] = d;
}

// ---------------- layer-0 only: als/ald = h @ Bs/Bd ----------------
__global__ void k_ab(const float* __restrict__ h, const float* __restrict__ Bs_l,
                     const float* __restrict__ Bd_l, float* __restrict__ als,
                     float* __restrict__ ald) {
    int idx = blockIdx.x * 256 + threadIdx.x;
    if (idx >= Nn * 8) return;
    int n = idx >> 3, slot = idx & 7;
    const float* B = (slot < 4) ? Bs_l : Bd_l;
    int hh = slot & 3;
    const float4* hr = (const float4*)(h + (size_t)n * 128);
    float s = 0.f;
#pragma unroll 8
    for (int kb = 0; kb < 32; kb++) {
        float4 hv = hr[kb];
        s += hv.x * B[(4 * kb + 0) * 4 + hh] + hv.y * B[(4 * kb + 1) * 4 + hh]
           + hv.z * B[(4 * kb + 2) * 4 + hh] + hv.w * B[(4 * kb + 3) * 4 + hh];
    }
    if (slot < 4) als[n * 4 + hh] = s;
    else          ald[n * 4 + hh] = s;
}

// ---- per-layer edge-parallel alpha: exv[i][h] = exp(leaky(als[src]+ald[dst]+ale)) ----
__global__ __launch_bounds__(256) void k_alpha(
    const int2* __restrict__ pse, const int* __restrict__ dstv,
    const float* __restrict__ als, const float* __restrict__ ald,
    const float* __restrict__ aleT_l, const float* __restrict__ lale_l,
    float* __restrict__ exv) {
    int i = blockIdx.x * 256 + threadIdx.x;
    if (i >= ET) return;
    int2 se = pse[i];
    int d = dstv[i];
    float4 as = *(const float4*)(als + (size_t)se.x * 4);
    float4 ad = *(const float4*)(ald + (size_t)d * 4);
    float4 ae = (se.y < Ee) ? *(const float4*)(aleT_l + (size_t)se.y * 4)
                            : *(const float4*)lale_l;
    float4 o;
    float a;
    a = as.x + ad.x + ae.x; a = a > 0.f ? a : 0.2f * a; o.x = __expf(fminf(a, 60.f));
    a = as.y + ad.y + ae.y; a = a > 0.f ? a : 0.2f * a; o.y = __expf(fminf(a, 60.f));
    a = as.z + ad.z + ae.z; a = a > 0.f ? a : 0.2f * a; o.z = __expf(fminf(a, 60.f));
    a = as.w + ad.w + ae.w; a = a > 0.f ? a : 0.2f * a; o.w = __expf(fminf(a, 60.f));
    *(float4*)(exv + (size_t)i * 4) = o;
}

// ---- per-layer agg: 1 wave per node, no LDS/no barrier, 4-edge unroll ----
__global__ __launch_bounds__(256, 6) void k_agg3(
    const int* __restrict__ srcv, const int* __restrict__ seg,
    const float* __restrict__ exv, const unsigned short* __restrict__ hb,
    unsigned short* __restrict__ aggb) {
    int t = threadIdx.x;
    int lane = t & 63, w = t >> 6;
    int n = blockIdx.x * 4 + w;
    int start = seg[n], end = seg[n + 1];
    int hp = lane >> 4;
    int cch = (lane & 15) * 8;
    float den = 0.f;
    float4 acc0 = make_float4(0.f, 0.f, 0.f, 0.f);
    float4 acc1 = make_float4(0.f, 0.f, 0.f, 0.f);
    int i = start;
    for (; i + 4 <= end; i += 4) {
        int s0 = srcv[i], s1 = srcv[i + 1], s2 = srcv[i + 2], s3 = srcv[i + 3];
        float e0 = exv[(size_t)(i + 0) * 4 + hp];
        float e1 = exv[(size_t)(i + 1) * 4 + hp];
        float e2 = exv[(size_t)(i + 2) * 4 + hp];
        float e3 = exv[(size_t)(i + 3) * 4 + hp];
        uint4 u0 = *(const uint4*)(hb + (size_t)s0 * 128 + cch);
        uint4 u1 = *(const uint4*)(hb + (size_t)s1 * 128 + cch);
        uint4 u2 = *(const uint4*)(hb + (size_t)s2 * 128 + cch);
        uint4 u3 = *(const uint4*)(hb + (size_t)s3 * 128 + cch);
        den += (e0 + e1) + (e2 + e3);
        acc0.x += (e0 * bflo(u0.x) + e1 * bflo(u1.x)) + (e2 * bflo(u2.x) + e3 * bflo(u3.x));
        acc0.y += (e0 * bfhi(u0.x) + e1 * bfhi(u1.x)) + (e2 * bfhi(u2.x) + e3 * bfhi(u3.x));
        acc0.z += (e0 * bflo(u0.y) + e1 * bflo(u1.y)) + (e2 * bflo(u2.y) + e3 * bflo(u3.y));
        acc0.w += (e0 * bfhi(u0.y) + e1 * bfhi(u1.y)) + (e2 * bfhi(u2.y) + e3 * bfhi(u3.y));
        acc1.x += (e0 * bflo(u0.z) + e1 * bflo(u1.z)) + (e2 * bflo(u2.z) + e3 * bflo(u3.z));
        acc1.y += (e0 * bfhi(u0.z) + e1 * bfhi(u1.z)) + (e2 * bfhi(u2.z) + e3 * bfhi(u3.z));
        acc1.z += (e0 * bflo(u0.w) + e1 * bflo(u1.w)) + (e2 * bflo(u2.w) + e3 * bflo(u3.w));
        acc1.w += (e0 * bfhi(u0.w) + e1 * bfhi(u1.w)) + (e2 * bfhi(u2.w) + e3 * bfhi(u3.w));
    }
    for (; i < end; i++) {
        int s0 = srcv[i];
        float e0 = exv[(size_t)i * 4 + hp];
        uint4 u0 = *(const uint4*)(hb + (size_t)s0 * 128 + cch);
        den += e0;
        acc0.x += e0 * bflo(u0.x); acc0.y += e0 * bfhi(u0.x);
        acc0.z += e0 * bflo(u0.y); acc0.w += e0 * bfhi(u0.y);
        acc1.x += e0 * bflo(u0.z); acc1.y += e0 * bfhi(u0.z);
        acc1.z += e0 * bflo(u0.w); acc1.w += e0 * bfhi(u0.w);
    }
    float inv = 1.f / (den + 1e-16f);
    ushort4 q0, q1;
    q0.x = f2bf(acc0.x * inv); q0.y = f2bf(acc0.y * inv);
    q0.z = f2bf(acc0.z * inv); q0.w = f2bf(acc0.w * inv);
    q1.x = f2bf(acc1.x * inv); q1.y = f2bf(acc1.y * inv);
    q1.z = f2bf(acc1.z * inv); q1.w = f2bf(acc1.w * inv);
    *(ushort4*)(aggb + (size_t)n * 512 + lane * 8) = q0;
    *(ushort4*)(aggb + (size_t)n * 512 + lane * 8 + 4) = q1;
}

// ---- per-layer: h_new = LN(relu(aggcat @ Wsum + gbias) + h); + next-layer als/ald ----
__global__ __launch_bounds__(256) void k_post(
    const unsigned short* __restrict__ aggb, const unsigned short* __restrict__ WsumT_l,
    const float* __restrict__ gbias, const float* __restrict__ lnsc,
    const float* __restrict__ lnbi, float* __restrict__ h,
    unsigned short* __restrict__ hb, const float* __restrict__ Bs_n,
    const float* __restrict__ Bd_n, float* __restrict__ als, float* __restrict__ ald) {
    int t = threadIdx.x;
    int lane = t & 63, w = t >> 6;
    int n0 = (blockIdx.x * 4 + w) * 16;
    if (n0 >= Nn) return;
    int m = lane & 15, q = lane >> 4;
    v4f acc[8];
#pragma unroll
    for (int nt = 0; nt < 8; nt++) acc[nt] = (v4f){0.f, 0.f, 0.f, 0.f};
    const unsigned short* arow = aggb + (size_t)(n0 + m) * 512 + q * 8;
#pragma unroll 4
    for (int ks = 0; ks < 16; ks++) {
        v8s fa = *(const v8s*)(arow + ks * 32);
#pragma unroll
        for (int nt = 0; nt < 8; nt++) {
            int col = nt * 16 + m;
            v8s fb = *(const v8s*)(WsumT_l + (size_t)col * 512 + ks * 32 + q * 8);
            acc[nt] = __builtin_amdgcn_mfma_f32_16x16x32_bf16(fa, fb, acc[nt], 0, 0, 0);
        }
    }
    float v[8][4];
    float s1[4] = {0.f, 0.f, 0.f, 0.f}, s2[4] = {0.f, 0.f, 0.f, 0.f};
#pragma unroll
    for (int nt = 0; nt < 8; nt++) {
        int col = nt * 16 + m;
        float b = gbias[col];
#pragma unroll
        for (int r = 0; r < 4; r++) {
            int row = n0 + q * 4 + r;
            float val = h[(size_t)row * 128 + col] + fmaxf(acc[nt][r] + b, 0.f);
            v[nt][r] = val;
            s1[r] += val; s2[r] += val * val;
        }
    }
#pragma unroll
    for (int d = 1; d <= 8; d <<= 1) {
#pragma unroll
        for (int r = 0; r < 4; r++) {
            s1[r] += __shfl_xor(s1[r], d);
            s2[r] += __shfl_xor(s2[r], d);
        }
    }
    float o8[8][4];
#pragma unroll
    for (int r = 0; r < 4; r++) {
        float mean = s1[r] * (1.f / 128.f);
        float var = s2[r] * (1.f / 128.f) - mean * mean;
        float rinv = rsqrtf(var + 1e-5f);
        int row = n0 + q * 4 + r;
#pragma unroll
        for (int nt = 0; nt < 8; nt++) {
            int col = nt * 16 + m;
            float o = (v[nt][r] - mean) * rinv * lnsc[col] + lnbi[col];
            o8[nt][r] = o;
            h[(size_t)row * 128 + col] = o;
            hb[(size_t)row * 128 + col] = f2bf(o);
        }
    }
    float sal[4][4], sad[4][4];
#pragma unroll
    for (int r = 0; r < 4; r++) {
#pragma unroll
        for (int hh = 0; hh < 4; hh++) { sal[r][hh] = 0.f; sad[r][hh] = 0.f; }
    }
#pragma unroll
    for (int nt = 0; nt < 8; nt++) {
        int col = nt * 16 + m;
        float4 bs = *(const float4*)(Bs_n + col * 4);
        float4 bd = *(const float4*)(Bd_n + col * 4);
#pragma unroll
        for (int r = 0; r < 4; r++) {
            float o = o8[nt][r];
            sal[r][0] += o * bs.x; sal[r][1] += o * bs.y;
            sal[r][2] += o * bs.z; sal[r][3] += o * bs.w;
            sad[r][0] += o * bd.x; sad[r][1] += o * bd.y;
            sad[r][2] += o * bd.z; sad[r][3] += o * bd.w;
        }
    }
#pragma unroll
    for (int d = 1; d <= 8; d <<= 1) {
#pragma unroll
        for (int r = 0; r < 4; r++) {
#pragma unroll
            for (int hh = 0; hh < 4; hh++) {
                sal[r][hh] += __shfl_xor(sal[r][hh], d);
                sad[r][hh] += __shfl_xor(sad[r][hh], d);
            }
        }
    }
    if (m < 8) {
        int hh = m & 3;
#pragma unroll
        for (int r = 0; r < 4; r++) {
            int row = n0 + q * 4 + r;
            float va = (hh == 0) ? sal[r][0] : (hh == 1) ? sal[r][1] : (hh == 2) ? sal[r][2] : sal[r][3];
            float vd = (hh == 0) ? sad[r][0] : (hh == 1) ? sad[r][1] : (hh == 2) ? sad[r][2] : sad[r][3];
            if (m < 4) als[row * 4 + hh] = va;
            else       ald[row * 4 + hh] = vd;
        }
    }
}

// ---------------- output projection ----------------
__global__ __launch_bounds__(256) void k_out(
    const float* __restrict__ h, const float* __restrict__ ow,
    const float* __restrict__ ob, float* __restrict__ out) {
    __shared__ float4 hs4[8][32];
    int t = threadIdx.x;
    int n0 = blockIdx.x * 8;
    if (t < 256) {
        int i = t >> 5, kb = t & 31;
        hs4[i][kb] = *(const float4*)(h + (size_t)(n0 + i) * 128 + 4 * kb);
    }
    __syncthreads();
    float acc[8] = {0, 0, 0, 0, 0, 0, 0, 0};
    for (int kb = 0; kb < 32; kb++) {
        float w0 = ow[(4 * kb + 0) * 256 + t];
        float w1 = ow[(4 * kb + 1) * 256 + t];
        float w2 = ow[(4 * kb + 2) * 256 + t];
        float w3 = ow[(4 * kb + 3) * 256 + t];
#pragma unroll
        for (int i = 0; i < 8; i++) {
            float4 hv = hs4[i][kb];
            acc[i] += hv.x * w0 + hv.y * w1 + hv.z * w2 + hv.w * w3;
        }
    }
    float b = ob[t];
#pragma unroll
    for (int i = 0; i < 8; i++) out[(size_t)(n0 + i) * 256 + t] = acc[i] + b;
}

extern "C" void kernel_launch(void* const* d_in, const int* in_sizes, int n_in,
                              void* d_out, int out_size, void* d_ws, size_t ws_size,
                              hipStream_t stream) {
    const float* x    = (const float*)d_in[0];
    const int*   ei   = (const int*)d_in[1];
    const float* ea   = (const float*)d_in[2];
    const float* vnfc = (const float*)d_in[3];
    const float* nw   = (const float*)d_in[4];
    const float* nb   = (const float*)d_in[5];
    const float* eaw  = (const float*)d_in[6];
    const float* eab  = (const float*)d_in[7];
    const float* vw   = (const float*)d_in[8];
    const float* vb   = (const float*)d_in[9];
    const float* a1w  = (const float*)d_in[10];
    const float* a1b  = (const float*)d_in[11];
    const float* a2w  = (const float*)d_in[12];
    const float* a2b  = (const float*)d_in[13];
    const float* a3w  = (const float*)d_in[14];
    const float* a3b  = (const float*)d_in[15];
    const float* glw  = (const float*)d_in[16];
    const float* gas  = (const float*)d_in[17];
    const float* gad  = (const float*)d_in[18];
    const float* glew = (const float*)d_in[19];
    const float* gae  = (const float*)d_in[20];
    const float* gb   = (const float*)d_in[21];
    const float* lnsc = (const float*)d_in[22];
    const float* lnbi = (const float*)d_in[23];
    const float* ow   = (const float*)d_in[24];
    const float* ob   = (const float*)d_in[25];
    float* out = (float*)d_out;

    char* w = (char*)d_ws;
    size_t o = 0;
    auto allocf = [&](size_t cnt) { float* p = (float*)(w + o); o += ((cnt * 4 + 255) / 256) * 256; return p; };
    auto alloci = [&](size_t cnt) { int* p = (int*)(w + o); o += ((cnt * 4 + 255) / 256) * 256; return p; };
    auto allocu = [&](size_t cnt) { unsigned short* p = (unsigned short*)(w + o); o += ((cnt * 2 + 255) / 256) * 256; return p; };
    float* h      = allocf((size_t)Nn * 128);
    unsigned short* hb    = allocu((size_t)Nn * 128);
    unsigned short* aggb  = allocu((size_t)Nn * 512);
    unsigned short* WsumT = allocu((size_t)LL * 128 * 512);
    unsigned short* w2bf  = allocu(8192);
    float* als    = allocf((size_t)Nn * 4);
    float* ald    = allocf((size_t)Nn * 4);
    float* aleT   = allocf((size_t)LL * Ee * 4);
    float* exv    = allocf((size_t)ET * 4);
    float* Bs     = allocf(3072);
    float* Bd     = allocf(3072);
    float* Be     = allocf(3072);
    float* E1     = allocf(1024);
    float* PB     = allocf(96);
    float* cB     = allocf(24);
    float* gsum   = allocf(8);
    float* lale   = allocf(32);
    int* seg  = alloci(Nn + 1);
    int* hist = alloci(Nn);
    int* pos  = alloci(Nn);
    int* srcv = alloci(ET);
    int* dstv = alloci(ET);
    int2* pse = (int2*)alloci((size_t)ET * 2);

    hipMemsetAsync(hist, 0, Nn * sizeof(int), stream);
    hipMemsetAsync(gsum, 0, 8 * sizeof(float), stream);

    k_node_embed<<<(Nn * 128 + 255) / 256, 256, 0, stream>>>(x, nw, nb, h, hb);
    k_small<<<1, 512, 0, stream>>>(vnfc, vw, vb, eab, a1w, a1b, eaw, E1);
    k_bmat<<<(LL * 128 * 4 + 255) / 256, 256, 0, stream>>>(glw, gas, gad, glew, gae, Bs, Bd, Be);
    k_wsum<<<(LL * 128 * 512 + 255) / 256, 256, 0, stream>>>(glw, WsumT);
    k_w2b<<<32, 256, 0, stream>>>(a2w, w2bf);
    k_pb<<<1, 32, 0, stream>>>(eaw, eab, Be, PB, cB);
    k_edge<<<Ee / 256, 256, 0, stream>>>(ea, E1, w2bf, a2b, a3w, a3b, PB, cB, aleT, gsum);
    k_hist<<<(ET + 255) / 256, 256, 0, stream>>>(ei, hist);
    k_scan<<<1, 1024, 0, stream>>>(hist, seg, pos);
    k_scatter<<<(ET + 255) / 256, 256, 0, stream>>>(ei, pos, pse, srcv, dstv);
    k_lale<<<1, 32, 0, stream>>>(gsum, PB, cB, lale);
    k_ab<<<(Nn * 8 + 255) / 256, 256, 0, stream>>>(h, Bs, Bd, als, ald);
    for (int l = 0; l < LL; l++) {
        int ln = (l + 1) % LL;
        k_alpha<<<(ET + 255) / 256, 256, 0, stream>>>(pse, dstv, als, ald,
                                                      aleT + (size_t)l * Ee * 4, lale + l * 4, exv);
        k_agg3<<<Nn / 4, 256, 0, stream>>>(srcv, seg, exv, hb, aggb);
        k_post<<<(625 + 3) / 4, 256, 0, stream>>>(aggb, WsumT + (size_t)l * 65536,
                                                  gb + l * 128, lnsc + l * 128, lnbi + l * 128,
                                                  h, hb, Bs + ln * 512, Bd + ln * 512, als, ald);
    }
    k_out<<<Nn / 8, 256, 0, stream>>>(h, ow, ob, out);
}

// Round 3
// 497.840 us; speedup vs baseline: 1.0801x; 1.0801x over previous
//
#include <hip/hip_runtime.h>
#include <hip/hip_bf16.h>
#include <math.h>

#define Nn 10000
#define Ee 160000
#define ET 170000   // Ee + Nn (self loops)
#define LL 6

typedef short v8s __attribute__((ext_vector_type(8)));
typedef float v4f __attribute__((ext_vector_type(4)));

__device__ __forceinline__ unsigned short f2bf(float v) {
    unsigned int b = __float_as_uint(v);
    b += 0x7fffu + ((b >> 16) & 1u);   // RNE
    return (unsigned short)(b >> 16);
}
__device__ __forceinline__ float bflo(unsigned int u) { return __uint_as_float(u << 16); }
__device__ __forceinline__ float bfhi(unsigned int u) { return __uint_as_float(u & 0xffff0000u); }

// ---- fused: node_embed (blocks 0..4999) + hist (5000..5664) + bmat (5665..5676) ----
__global__ __launch_bounds__(256) void k_first(
    const float* __restrict__ x, const float* __restrict__ nw,
    const float* __restrict__ nb, float* __restrict__ h, unsigned short* __restrict__ hb,
    const int* __restrict__ ei, int* __restrict__ hist,
    const float* __restrict__ glw, const float* __restrict__ gas,
    const float* __restrict__ gad, const float* __restrict__ glew,
    const float* __restrict__ gae, float* __restrict__ Bs,
    float* __restrict__ Bd, float* __restrict__ Be) {
    int b = blockIdx.x, t = threadIdx.x;
    if (b < 5000) {             // node embedding: h = x @ node_w + node_b
        int idx = b * 256 + t;
        int n = idx >> 7, c = idx & 127;
        const float* xr = x + (size_t)n * 8;
        float acc = nb[c];
#pragma unroll
        for (int k = 0; k < 8; k++) acc += xr[k] * nw[k * 128 + c];
        h[idx] = acc;
        hb[idx] = f2bf(acc);
        return;
    }
    if (b < 5665) {             // degree histogram
        int i = (b - 5000) * 256 + t;
        if (i < ET) {
            int d = (i < Ee) ? ei[Ee + i] : (i - Ee);
            atomicAdd(&hist[d], 1);
        }
        return;
    }
    {                           // Bs/Bd/Be [L][128][4]
        int idx = (b - 5665) * 256 + t;
        if (idx >= LL * 128 * 4) return;
        int hh = idx & 3, k = (idx >> 2) & 127, l = idx >> 9;
        const float* lwp = glw  + (size_t)l * 65536 + k * 512 + hh * 128;
        const float* lep = glew + (size_t)l * 65536 + k * 512 + hh * 128;
        const float* sp = gas + l * 512 + hh * 128;
        const float* dp = gad + l * 512 + hh * 128;
        const float* ep = gae + l * 512 + hh * 128;
        float s1 = 0, s2 = 0, s3 = 0;
        for (int c = 0; c < 128; c++) {
            float lv = lwp[c];
            s1 += lv * sp[c];
            s2 += lv * dp[c];
            s3 += lep[c] * ep[c];
        }
        Bs[idx] = s1; Bd[idx] = s2; Be[idx] = s3;
    }
}

// ---- fused setup: wsum (0..1535) + w2b (1536..1567) + small (1568) + pb (1569) ----
// pb reads Be produced by k_first (previous launch) -- no intra-kernel dependency.
__global__ __launch_bounds__(256) void k_setup(
    const float* __restrict__ glw, unsigned short* __restrict__ WsumT,
    const float* __restrict__ a2w, unsigned short* __restrict__ w2bf,
    const float* __restrict__ vnfc, const float* __restrict__ vw,
    const float* __restrict__ vb, const float* __restrict__ eab,
    const float* __restrict__ a1w, const float* __restrict__ a1b,
    const float* __restrict__ eaw, float* __restrict__ E1,
    const float* __restrict__ Be, float* __restrict__ PB, float* __restrict__ cB) {
    __shared__ float vr[128];
    __shared__ float sM1[512];
    __shared__ float sd1[128];
    int b = blockIdx.x, t = threadIdx.x;
    if (b < 1536) {             // WsumT[l][c][kk] = bf16(0.25 * lw^T)
        int idx = b * 256 + t;
        int kk = idx & 511;
        int c = (idx >> 9) & 127;
        int l = idx >> 16;
        float v = 0.25f * glw[(size_t)l * 65536 + (size_t)(kk & 127) * 512 + (kk >> 7) * 128 + c];
        WsumT[(size_t)l * 65536 + (size_t)c * 512 + kk] = f2bf(v);
        return;
    }
    if (b < 1568) {             // w2 -> bf16 MFMA B-fragment order
        int idx = (b - 1536) * 256 + t;
        int j = idx & 7, lane = (idx >> 3) & 63, nt = (idx >> 9) & 3, ks = idx >> 11;
        int k = ks * 32 + ((lane >> 4) << 3) + j;
        int n = nt * 16 + (lane & 15);
        w2bf[idx] = f2bf(a2w[k * 64 + n]);
        return;
    }
    if (b == 1568) {            // E1[128][8] = {M1[0..3][k], d1[k], 0,0,0}
        if (t < 128) {
            float a = vb[t];
#pragma unroll
            for (int k = 0; k < 6; k++) a += vnfc[k] * vw[k * 128 + t];
            vr[t] = a;
        }
        __syncthreads();
        if (t < 128) {
            float a = a1b[t];
            for (int k = 0; k < 128; k++) a += eab[k] * a1w[k * 128 + t];
            for (int k = 0; k < 128; k++) a += vr[k] * a1w[(128 + k) * 128 + t];
            sd1[t] = a;
        }
#pragma unroll
        for (int rr = 0; rr < 2; rr++) {
            int id = rr * 256 + t;
            int r = id >> 7, j = id & 127;
            float a = 0.f;
            for (int k = 0; k < 128; k++) a += eaw[r * 128 + k] * a1w[k * 128 + j];
            sM1[id] = a;
        }
        __syncthreads();
        if (t < 128) {
            E1[t * 8 + 0] = sM1[t];
            E1[t * 8 + 1] = sM1[128 + t];
            E1[t * 8 + 2] = sM1[256 + t];
            E1[t * 8 + 3] = sM1[384 + t];
            E1[t * 8 + 4] = sd1[t];
            E1[t * 8 + 5] = 0.f; E1[t * 8 + 6] = 0.f; E1[t * 8 + 7] = 0.f;
        }
        return;
    }
    {                           // PB[4][24], cB[24]
        if (t >= 24) return;
        int l = t >> 2, hh = t & 3;
        const float* bp = Be + l * 512 + hh;
        float s0 = 0, s1 = 0, s2 = 0, s3 = 0, sc = 0;
        for (int k = 0; k < 128; k++) {
            float bv = bp[k * 4];
            s0 += eaw[0 * 128 + k] * bv;
            s1 += eaw[1 * 128 + k] * bv;
            s2 += eaw[2 * 128 + k] * bv;
            s3 += eaw[3 * 128 + k] * bv;
            sc += eab[k] * bv;
        }
        PB[0 * 24 + t] = s0; PB[1 * 24 + t] = s1;
        PB[2 * 24 + t] = s2; PB[3 * 24 + t] = s3;
        cB[t] = sc;
    }
}

// ---------------- prefix scan over hist ----------------
__global__ __launch_bounds__(1024) void k_scan(const int* __restrict__ hist,
                                               int* __restrict__ seg, int* __restrict__ pos) {
    __shared__ int wsums[16];
    __shared__ int carry_s;
    int t = threadIdx.x;
    int lane = t & 63, wid = t >> 6;
    if (t == 0) { carry_s = 0; seg[0] = 0; }
    __syncthreads();
    for (int base = 0; base < Nn; base += 1024) {
        int idx = base + t;
        int v = (idx < Nn) ? hist[idx] : 0;
        int sc = v;
#pragma unroll
        for (int d = 1; d < 64; d <<= 1) {
            int up = __shfl_up(sc, d);
            if (lane >= d) sc += up;
        }
        if (lane == 63) wsums[wid] = sc;
        __syncthreads();
        if (wid == 0) {
            int wv = (lane < 16) ? wsums[lane] : 0;
            int wsc = wv;
#pragma unroll
            for (int d = 1; d < 16; d <<= 1) {
                int up = __shfl_up(wsc, d);
                if (lane >= d) wsc += up;
            }
            if (lane < 16) wsums[lane] = wsc - wv;
        }
        __syncthreads();
        int carry = carry_s;
        int inc = sc + wsums[wid] + carry;
        if (idx < Nn) { seg[idx + 1] = inc; pos[idx] = inc - v; }
        __syncthreads();
        if (t == 1023) carry_s = inc;
        __syncthreads();
    }
}

// ---- scatter: srcv per sorted slot; inv (orig edge -> slot); loopslot per node ----
__global__ void k_scatter(const int* __restrict__ ei, int* __restrict__ pos,
                          int* __restrict__ srcv, int* __restrict__ inv,
                          int* __restrict__ loopslot) {
    int i = blockIdx.x * 256 + threadIdx.x;
    if (i >= ET) return;
    int s, d;
    if (i < Ee) { s = ei[i]; d = ei[Ee + i]; } else { s = d = i - Ee; }
    int idx = atomicAdd(&pos[d], 1);
    srcv[idx] = s;
    if (i < Ee) inv[i] = idx;
    else        loopslot[i - Ee] = idx;
}

// ---- edge gate MLP (MFMA); writes aleT directly into dst-sorted slots via inv ----
__global__ __launch_bounds__(256, 2) void k_edge(
    const float* __restrict__ ea, const float* __restrict__ E1,
    const unsigned short* __restrict__ w2bf,
    const float* __restrict__ a2b, const float* __restrict__ a3w,
    const float* __restrict__ a3b,
    const float* __restrict__ PB, const float* __restrict__ cB,
    const int* __restrict__ inv,
    float* __restrict__ aleT, float* __restrict__ gsum) {
    __shared__ float4 sM[128];     // swizzled: row k stored at k ^ ((k>>3)&3)
    __shared__ float sD[128];
    __shared__ float4 sevs[256];
    __shared__ float gsh[256];
    __shared__ float sgsum[5];
    int t = threadIdx.x;
    int lane = t & 63;
    int wid = t >> 6;
    int c = lane & 15, q = lane >> 4;
    int eb0 = blockIdx.x * 256;

    sevs[t] = *(const float4*)(ea + (size_t)(eb0 + t) * 4);
    if (t < 128) {
        int slot = t ^ ((t >> 3) & 3);
        sM[slot] = *(const float4*)(E1 + t * 8);
        sD[t] = E1[t * 8 + 4];
    }
    if (t < 5) sgsum[t] = 0.f;
    __syncthreads();

    float4 ev4[4];
#pragma unroll
    for (int mt = 0; mt < 4; mt++) ev4[mt] = sevs[(wid * 4 + mt) * 16 + c];

    // layer 1: hidden1 -> bf16 A-fragments
    v8s av[4][4];
#pragma unroll
    for (int ks = 0; ks < 4; ks++) {
        float4 mr[8]; float dr[8];
#pragma unroll
        for (int j = 0; j < 8; j++) {
            int k = ks * 32 + q * 8 + j;
            mr[j] = sM[k ^ q];
            dr[j] = sD[k];
        }
#pragma unroll
        for (int mt = 0; mt < 4; mt++) {
            float4 ev = ev4[mt];
            v8s a;
#pragma unroll
            for (int j = 0; j < 8; j++) {
                float xv = fmaxf(dr[j] + ev.x * mr[j].x + ev.y * mr[j].y
                                       + ev.z * mr[j].z + ev.w * mr[j].w, 0.f);
                a[j] = (short)f2bf(xv);
            }
            av[mt][ks] = a;
        }
    }

    // layer 2: MFMA, bias in C-init
    v4f acc[4][4];
#pragma unroll
    for (int nt = 0; nt < 4; nt++) {
        float bb = a2b[nt * 16 + c];
#pragma unroll
        for (int mt = 0; mt < 4; mt++) acc[mt][nt] = (v4f){bb, bb, bb, bb};
    }
#pragma unroll
    for (int nt = 0; nt < 4; nt++) {
#pragma unroll
        for (int ks = 0; ks < 4; ks++) {
            v8s bfr = *(const v8s*)(w2bf + ((size_t)(ks * 4 + nt) * 64 + lane) * 8);
#pragma unroll
            for (int mt = 0; mt < 4; mt++)
                acc[mt][nt] = __builtin_amdgcn_mfma_f32_16x16x32_bf16(av[mt][ks], bfr, acc[mt][nt], 0, 0, 0);
        }
    }

    // layer 3 + sigmoid
    float a3r[4];
#pragma unroll
    for (int nt = 0; nt < 4; nt++) a3r[nt] = a3w[nt * 16 + c];
    float a3b0 = a3b[0];
#pragma unroll
    for (int mt = 0; mt < 4; mt++) {
#pragma unroll
        for (int r = 0; r < 4; r++) {
            float s = 0.f;
#pragma unroll
            for (int nt = 0; nt < 4; nt++) s += fmaxf(acc[mt][nt][r], 0.f) * a3r[nt];
            s += __shfl_xor(s, 1); s += __shfl_xor(s, 2);
            s += __shfl_xor(s, 4); s += __shfl_xor(s, 8);
            if (c == 0) gsh[(wid * 4 + mt) * 16 + q * 4 + r] = 1.f / (1.f + __expf(-(s + a3b0)));
        }
    }
    __syncthreads();

    // per-edge epilogue
    float g = gsh[t];
    float4 evv = sevs[t];
    float v0 = g, v1 = g * evv.x, v2 = g * evv.y, v3 = g * evv.z, v4 = g * evv.w;
#pragma unroll
    for (int d = 32; d > 0; d >>= 1) {
        v0 += __shfl_down(v0, d); v1 += __shfl_down(v1, d); v2 += __shfl_down(v2, d);
        v3 += __shfl_down(v3, d); v4 += __shfl_down(v4, d);
    }
    if (lane == 0) {
        atomicAdd(&sgsum[0], v0); atomicAdd(&sgsum[1], v1); atomicAdd(&sgsum[2], v2);
        atomicAdd(&sgsum[3], v3); atomicAdd(&sgsum[4], v4);
    }
    __syncthreads();
    if (t < 5) atomicAdd(&gsum[t], sgsum[t]);
    int slot = inv[eb0 + t];
#pragma unroll
    for (int i4 = 0; i4 < 6; i4++) {
        float4 cc = *(const float4*)(cB + i4 * 4);
        float4 p0 = *(const float4*)(PB + 0 * 24 + i4 * 4);
        float4 p1 = *(const float4*)(PB + 1 * 24 + i4 * 4);
        float4 p2 = *(const float4*)(PB + 2 * 24 + i4 * 4);
        float4 p3 = *(const float4*)(PB + 3 * 24 + i4 * 4);
        float4 o;
        o.x = g * (cc.x + evv.x * p0.x + evv.y * p1.x + evv.z * p2.x + evv.w * p3.x);
        o.y = g * (cc.y + evv.x * p0.y + evv.y * p1.y + evv.z * p2.y + evv.w * p3.y);
        o.z = g * (cc.z + evv.x * p0.z + evv.y * p1.z + evv.z * p2.z + evv.w * p3.z);
        o.w = g * (cc.w + evv.x * p0.w + evv.y * p1.w + evv.z * p2.w + evv.w * p3.w);
        *(float4*)(aleT + (size_t)i4 * ET * 4 + (size_t)slot * 4) = o;
    }
}

// ---- fused: als/ald layer0 (blocks 0..312) + self-loop lale fill (313..547) ----
__global__ __launch_bounds__(256) void k_abfill(
    const float* __restrict__ h, const float* __restrict__ Bs_l,
    const float* __restrict__ Bd_l, float* __restrict__ als, float* __restrict__ ald,
    const int* __restrict__ loopslot, const float* __restrict__ gsum,
    const float* __restrict__ PB, const float* __restrict__ cB,
    float* __restrict__ aleT) {
    int b = blockIdx.x, t = threadIdx.x;
    if (b < 313) {
        int idx = b * 256 + t;
        if (idx >= Nn * 8) return;
        int n = idx >> 3, slot = idx & 7;
        const float* B = (slot < 4) ? Bs_l : Bd_l;
        int hh = slot & 3;
        const float4* hr = (const float4*)(h + (size_t)n * 128);
        float s = 0.f;
#pragma unroll 8
        for (int kb = 0; kb < 32; kb++) {
            float4 hv = hr[kb];
            s += hv.x * B[(4 * kb + 0) * 4 + hh] + hv.y * B[(4 * kb + 1) * 4 + hh]
               + hv.z * B[(4 * kb + 2) * 4 + hh] + hv.w * B[(4 * kb + 3) * 4 + hh];
        }
        if (slot < 4) als[n * 4 + hh] = s;
        else          ald[n * 4 + hh] = s;
        return;
    }
    {
        int idx = (b - 313) * 256 + t;
        if (idx >= LL * Nn) return;
        int l = idx / Nn;
        int j = idx - l * Nn;
        int slot = loopslot[j];
        float g0 = gsum[0], g1 = gsum[1], g2 = gsum[2], g3 = gsum[3], g4 = gsum[4];
        float4 cc = *(const float4*)(cB + l * 4);
        float4 p0 = *(const float4*)(PB + 0 * 24 + l * 4);
        float4 p1 = *(const float4*)(PB + 1 * 24 + l * 4);
        float4 p2 = *(const float4*)(PB + 2 * 24 + l * 4);
        float4 p3 = *(const float4*)(PB + 3 * 24 + l * 4);
        float4 o;
        o.x = (g0 * cc.x + g1 * p0.x + g2 * p1.x + g3 * p2.x + g4 * p3.x) * (1.0f / Ee);
        o.y = (g0 * cc.y + g1 * p0.y + g2 * p1.y + g3 * p2.y + g4 * p3.y) * (1.0f / Ee);
        o.z = (g0 * cc.z + g1 * p0.z + g2 * p1.z + g3 * p2.z + g4 * p3.z) * (1.0f / Ee);
        o.w = (g0 * cc.w + g1 * p0.w + g2 * p1.w + g3 * p2.w + g4 * p3.w) * (1.0f / Ee);
        *(float4*)(aleT + (size_t)l * ET * 4 + (size_t)slot * 4) = o;
    }
}

// ---- per-layer agg: single-pass no-max softmax; 2 waves/node, 2 nodes/block ----
// aleS_l is dst-sorted (self-loop slots pre-filled) -> streaming read, no branch.
__global__ __launch_bounds__(256) void k_agg3(
    const int* __restrict__ srcv, const int* __restrict__ seg,
    const float* __restrict__ als, const float* __restrict__ ald,
    const float* __restrict__ aleS_l,
    const unsigned short* __restrict__ hb, unsigned short* __restrict__ aggb) {
    __shared__ float part[2][512];
    __shared__ float pden[2][4];
    int t = threadIdx.x;
    int lane = t & 63;
    int wv = (t >> 6) & 1;
    int w = t >> 7;
    int n = blockIdx.x * 2 + w;
    int start = seg[n], end = seg[n + 1];
    int deg = end - start;
    int half = (deg + 1) >> 1;
    int s0 = start + wv * half;
    int e0 = wv ? end : start + half;
    int hp = lane >> 4;
    int cch = (lane & 15) * 8;
    float aldh = ald[n * 4 + hp];
    float den = 0.f;
    float4 acc0 = make_float4(0.f, 0.f, 0.f, 0.f);
    float4 acc1 = make_float4(0.f, 0.f, 0.f, 0.f);
    int i = s0;
    for (; i + 2 <= e0; i += 2) {
        int sa = srcv[i], sb = srcv[i + 1];
        float ala = aleS_l[(size_t)i * 4 + hp];
        float alb = aleS_l[(size_t)(i + 1) * 4 + hp];
        float ava = als[sa * 4 + hp] + aldh + ala;
        float avb = als[sb * 4 + hp] + aldh + alb;
        ava = ava > 0.f ? ava : 0.2f * ava;
        avb = avb > 0.f ? avb : 0.2f * avb;
        float ea = __expf(fminf(ava, 60.f));
        float eb = __expf(fminf(avb, 60.f));
        den += ea + eb;
        uint4 ua = *(const uint4*)(hb + (size_t)sa * 128 + cch);
        uint4 ub = *(const uint4*)(hb + (size_t)sb * 128 + cch);
        acc0.x += ea * bflo(ua.x) + eb * bflo(ub.x);
        acc0.y += ea * bfhi(ua.x) + eb * bfhi(ub.x);
        acc0.z += ea * bflo(ua.y) + eb * bflo(ub.y);
        acc0.w += ea * bfhi(ua.y) + eb * bfhi(ub.y);
        acc1.x += ea * bflo(ua.z) + eb * bflo(ub.z);
        acc1.y += ea * bfhi(ua.z) + eb * bfhi(ub.z);
        acc1.z += ea * bflo(ua.w) + eb * bflo(ub.w);
        acc1.w += ea * bfhi(ua.w) + eb * bfhi(ub.w);
    }
    if (i < e0) {
        int sa = srcv[i];
        float ala = aleS_l[(size_t)i * 4 + hp];
        float ava = als[sa * 4 + hp] + aldh + ala;
        ava = ava > 0.f ? ava : 0.2f * ava;
        float ea = __expf(fminf(ava, 60.f));
        den += ea;
        uint4 ua = *(const uint4*)(hb + (size_t)sa * 128 + cch);
        acc0.x += ea * bflo(ua.x); acc0.y += ea * bfhi(ua.x);
        acc0.z += ea * bflo(ua.y); acc0.w += ea * bfhi(ua.y);
        acc1.x += ea * bflo(ua.z); acc1.y += ea * bfhi(ua.z);
        acc1.z += ea * bflo(ua.w); acc1.w += ea * bfhi(ua.w);
    }
    if (wv == 1) {
        *(float4*)&part[w][lane * 8] = acc0;
        *(float4*)&part[w][lane * 8 + 4] = acc1;
        if ((lane & 15) == 0) pden[w][hp] = den;
    }
    __syncthreads();
    if (wv == 0) {
        float4 p0 = *(const float4*)&part[w][lane * 8];
        float4 p1 = *(const float4*)&part[w][lane * 8 + 4];
        float inv2 = 1.f / (den + pden[w][hp] + 1e-16f);
        acc0.x = (acc0.x + p0.x) * inv2; acc0.y = (acc0.y + p0.y) * inv2;
        acc0.z = (acc0.z + p0.z) * inv2; acc0.w = (acc0.w + p0.w) * inv2;
        acc1.x = (acc1.x + p1.x) * inv2; acc1.y = (acc1.y + p1.y) * inv2;
        acc1.z = (acc1.z + p1.z) * inv2; acc1.w = (acc1.w + p1.w) * inv2;
        ushort4 q0, q1;
        q0.x = f2bf(acc0.x); q0.y = f2bf(acc0.y); q0.z = f2bf(acc0.z); q0.w = f2bf(acc0.w);
        q1.x = f2bf(acc1.x); q1.y = f2bf(acc1.y); q1.z = f2bf(acc1.z); q1.w = f2bf(acc1.w);
        *(ushort4*)(aggb + (size_t)n * 512 + lane * 8) = q0;
        *(ushort4*)(aggb + (size_t)n * 512 + lane * 8 + 4) = q1;
    }
}

// ---- per-layer: h_new = LN(relu(aggcat @ Wsum + gbias) + h); + next-layer als/ald ----
__global__ __launch_bounds__(256) void k_post(
    const unsigned short* __restrict__ aggb, const unsigned short* __restrict__ WsumT_l,
    const float* __restrict__ gbias, const float* __restrict__ lnsc,
    const float* __restrict__ lnbi, float* __restrict__ h,
    unsigned short* __restrict__ hb, const float* __restrict__ Bs_n,
    const float* __restrict__ Bd_n, float* __restrict__ als, float* __restrict__ ald) {
    int t = threadIdx.x;
    int lane = t & 63, w = t >> 6;
    int n0 = (blockIdx.x * 4 + w) * 16;
    if (n0 >= Nn) return;
    int m = lane & 15, q = lane >> 4;
    v4f acc[8];
#pragma unroll
    for (int nt = 0; nt < 8; nt++) acc[nt] = (v4f){0.f, 0.f, 0.f, 0.f};
    const unsigned short* arow = aggb + (size_t)(n0 + m) * 512 + q * 8;
#pragma unroll 4
    for (int ks = 0; ks < 16; ks++) {
        v8s fa = *(const v8s*)(arow + ks * 32);
#pragma unroll
        for (int nt = 0; nt < 8; nt++) {
            int col = nt * 16 + m;
            v8s fb = *(const v8s*)(WsumT_l + (size_t)col * 512 + ks * 32 + q * 8);
            acc[nt] = __builtin_amdgcn_mfma_f32_16x16x32_bf16(fa, fb, acc[nt], 0, 0, 0);
        }
    }
    float v[8][4];
    float s1[4] = {0.f, 0.f, 0.f, 0.f}, s2[4] = {0.f, 0.f, 0.f, 0.f};
#pragma unroll
    for (int nt = 0; nt < 8; nt++) {
        int col = nt * 16 + m;
        float b = gbias[col];
#pragma unroll
        for (int r = 0; r < 4; r++) {
            int row = n0 + q * 4 + r;
            float val = h[(size_t)row * 128 + col] + fmaxf(acc[nt][r] + b, 0.f);
            v[nt][r] = val;
            s1[r] += val; s2[r] += val * val;
        }
    }
#pragma unroll
    for (int d = 1; d <= 8; d <<= 1) {
#pragma unroll
        for (int r = 0; r < 4; r++) {
            s1[r] += __shfl_xor(s1[r], d);
            s2[r] += __shfl_xor(s2[r], d);
        }
    }
    float o8[8][4];
#pragma unroll
    for (int r = 0; r < 4; r++) {
        float mean = s1[r] * (1.f / 128.f);
        float var = s2[r] * (1.f / 128.f) - mean * mean;
        float rinv = rsqrtf(var + 1e-5f);
        int row = n0 + q * 4 + r;
#pragma unroll
        for (int nt = 0; nt < 8; nt++) {
            int col = nt * 16 + m;
            float o = (v[nt][r] - mean) * rinv * lnsc[col] + lnbi[col];
            o8[nt][r] = o;
            h[(size_t)row * 128 + col] = o;
            hb[(size_t)row * 128 + col] = f2bf(o);
        }
    }
    float sal[4][4], sad[4][4];
#pragma unroll
    for (int r = 0; r < 4; r++) {
#pragma unroll
        for (int hh = 0; hh < 4; hh++) { sal[r][hh] = 0.f; sad[r][hh] = 0.f; }
    }
#pragma unroll
    for (int nt = 0; nt < 8; nt++) {
        int col = nt * 16 + m;
        float4 bs = *(const float4*)(Bs_n + col * 4);
        float4 bd = *(const float4*)(Bd_n + col * 4);
#pragma unroll
        for (int r = 0; r < 4; r++) {
            float o = o8[nt][r];
            sal[r][0] += o * bs.x; sal[r][1] += o * bs.y;
            sal[r][2] += o * bs.z; sal[r][3] += o * bs.w;
            sad[r][0] += o * bd.x; sad[r][1] += o * bd.y;
            sad[r][2] += o * bd.z; sad[r][3] += o * bd.w;
        }
    }
#pragma unroll
    for (int d = 1; d <= 8; d <<= 1) {
#pragma unroll
        for (int r = 0; r < 4; r++) {
#pragma unroll
            for (int hh = 0; hh < 4; hh++) {
                sal[r][hh] += __shfl_xor(sal[r][hh], d);
                sad[r][hh] += __shfl_xor(sad[r][hh], d);
            }
        }
    }
    if (m < 8) {
        int hh = m & 3;
#pragma unroll
        for (int r = 0; r < 4; r++) {
            int row = n0 + q * 4 + r;
            float va = (hh == 0) ? sal[r][0] : (hh == 1) ? sal[r][1] : (hh == 2) ? sal[r][2] : sal[r][3];
            float vd = (hh == 0) ? sad[r][0] : (hh == 1) ? sad[r][1] : (hh == 2) ? sad[r][2] : sad[r][3];
            if (m < 4) als[row * 4 + hh] = va;
            else       ald[row * 4 + hh] = vd;
        }
    }
}

// ---------------- output projection ----------------
__global__ __launch_bounds__(256) void k_out(
    const float* __restrict__ h, const float* __restrict__ ow,
    const float* __restrict__ ob, float* __restrict__ out) {
    __shared__ float4 hs4[8][32];
    int t = threadIdx.x;
    int n0 = blockIdx.x * 8;
    if (t < 256) {
        int i = t >> 5, kb = t & 31;
        hs4[i][kb] = *(const float4*)(h + (size_t)(n0 + i) * 128 + 4 * kb);
    }
    __syncthreads();
    float acc[8] = {0, 0, 0, 0, 0, 0, 0, 0};
    for (int kb = 0; kb < 32; kb++) {
        float w0 = ow[(4 * kb + 0) * 256 + t];
        float w1 = ow[(4 * kb + 1) * 256 + t];
        float w2 = ow[(4 * kb + 2) * 256 + t];
        float w3 = ow[(4 * kb + 3) * 256 + t];
#pragma unroll
        for (int i = 0; i < 8; i++) {
            float4 hv = hs4[i][kb];
            acc[i] += hv.x * w0 + hv.y * w1 + hv.z * w2 + hv.w * w3;
        }
    }
    float b = ob[t];
#pragma unroll
    for (int i = 0; i < 8; i++) out[(size_t)(n0 + i) * 256 + t] = acc[i] + b;
}

extern "C" void kernel_launch(void* const* d_in, const int* in_sizes, int n_in,
                              void* d_out, int out_size, void* d_ws, size_t ws_size,
                              hipStream_t stream) {
    const float* x    = (const float*)d_in[0];
    const int*   ei   = (const int*)d_in[1];
    const float* ea   = (const float*)d_in[2];
    const float* vnfc = (const float*)d_in[3];
    const float* nw   = (const float*)d_in[4];
    const float* nb   = (const float*)d_in[5];
    const float* eaw  = (const float*)d_in[6];
    const float* eab  = (const float*)d_in[7];
    const float* vw   = (const float*)d_in[8];
    const float* vb   = (const float*)d_in[9];
    const float* a1w  = (const float*)d_in[10];
    const float* a1b  = (const float*)d_in[11];
    const float* a2w  = (const float*)d_in[12];
    const float* a2b  = (const float*)d_in[13];
    const float* a3w  = (const float*)d_in[14];
    const float* a3b  = (const float*)d_in[15];
    const float* glw  = (const float*)d_in[16];
    const float* gas  = (const float*)d_in[17];
    const float* gad  = (const float*)d_in[18];
    const float* glew = (const float*)d_in[19];
    const float* gae  = (const float*)d_in[20];
    const float* gb   = (const float*)d_in[21];
    const float* lnsc = (const float*)d_in[22];
    const float* lnbi = (const float*)d_in[23];
    const float* ow   = (const float*)d_in[24];
    const float* ob   = (const float*)d_in[25];
    float* out = (float*)d_out;

    char* w = (char*)d_ws;
    size_t o = 0;
    auto allocf = [&](size_t cnt) { float* p = (float*)(w + o); o += ((cnt * 4 + 255) / 256) * 256; return p; };
    auto alloci = [&](size_t cnt) { int* p = (int*)(w + o); o += ((cnt * 4 + 255) / 256) * 256; return p; };
    auto allocu = [&](size_t cnt) { unsigned short* p = (unsigned short*)(w + o); o += ((cnt * 2 + 255) / 256) * 256; return p; };
    float* h      = allocf((size_t)Nn * 128);
    unsigned short* hb    = allocu((size_t)Nn * 128);
    unsigned short* aggb  = allocu((size_t)Nn * 512);
    unsigned short* WsumT = allocu((size_t)LL * 128 * 512);
    unsigned short* w2bf  = allocu(8192);
    float* als    = allocf((size_t)Nn * 4);
    float* ald    = allocf((size_t)Nn * 4);
    float* aleT   = allocf((size_t)LL * ET * 4);   // dst-sorted slots
    float* Bs     = allocf(3072);
    float* Bd     = allocf(3072);
    float* Be     = allocf(3072);
    float* E1     = allocf(1024);
    float* PB     = allocf(96);
    float* cB     = allocf(24);
    float* gsum   = allocf(8);
    int* seg      = alloci(Nn + 1);
    int* hist     = alloci(Nn);
    int* pos      = alloci(Nn);
    int* srcv     = alloci(ET);
    int* inv      = alloci(Ee);
    int* loopslot = alloci(Nn);

    hipMemsetAsync(hist, 0, Nn * sizeof(int), stream);
    hipMemsetAsync(gsum, 0, 8 * sizeof(float), stream);

    k_first<<<5677, 256, 0, stream>>>(x, nw, nb, h, hb, ei, hist,
                                      glw, gas, gad, glew, gae, Bs, Bd, Be);
    k_setup<<<1570, 256, 0, stream>>>(glw, WsumT, a2w, w2bf, vnfc, vw, vb, eab,
                                      a1w, a1b, eaw, E1, Be, PB, cB);
    k_scan<<<1, 1024, 0, stream>>>(hist, seg, pos);
    k_scatter<<<(ET + 255) / 256, 256, 0, stream>>>(ei, pos, srcv, inv, loopslot);
    k_edge<<<Ee / 256, 256, 0, stream>>>(ea, E1, w2bf, a2b, a3w, a3b, PB, cB, inv, aleT, gsum);
    k_abfill<<<548, 256, 0, stream>>>(h, Bs, Bd, als, ald, loopslot, gsum, PB, cB, aleT);
    for (int l = 0; l < LL; l++) {
        int ln = (l + 1) % LL;
        k_agg3<<<Nn / 2, 256, 0, stream>>>(srcv, seg, als, ald,
                                           aleT + (size_t)l * ET * 4, hb, aggb);
        k_post<<<(625 + 3) / 4, 256, 0, stream>>>(aggb, WsumT + (size_t)l * 65536,
                                                  gb + l * 128, lnsc + l * 128, lnbi + l * 128,
                                                  h, hb, Bs + ln * 512, Bd + ln * 512, als, ald);
    }
    k_out<<<Nn / 8, 256, 0, stream>>>(h, ow, ob, out);
}

// Round 4
// 476.069 us; speedup vs baseline: 1.1295x; 1.0457x over previous
//
#include <hip/hip_runtime.h>
#include <hip/hip_bf16.h>
#include <math.h>

#define Nn 10000
#define Ee 160000
#define ET 170000   // Ee + Nn (self loops)
#define LL 6

typedef short v8s __attribute__((ext_vector_type(8)));
typedef float v4f __attribute__((ext_vector_type(4)));

__device__ __forceinline__ unsigned short f2bf(float v) {
    unsigned int b = __float_as_uint(v);
    b += 0x7fffu + ((b >> 16) & 1u);   // RNE
    return (unsigned short)(b >> 16);
}
__device__ __forceinline__ float bflo(unsigned int u) { return __uint_as_float(u << 16); }
__device__ __forceinline__ float bfhi(unsigned int u) { return __uint_as_float(u & 0xffff0000u); }

// ---- fused: embed(0..4999) + hist(5000..5664) + bmat(5665..5676) + wsum(5677..7212)
//      + w2b(7213..7244) + small/E1(7245) ----
__global__ __launch_bounds__(256) void k_first(
    const float* __restrict__ x, const float* __restrict__ nw,
    const float* __restrict__ nb, float* __restrict__ h, unsigned short* __restrict__ hb,
    const int* __restrict__ ei, int* __restrict__ hist,
    const float* __restrict__ glw, const float* __restrict__ gas,
    const float* __restrict__ gad, const float* __restrict__ glew,
    const float* __restrict__ gae, float* __restrict__ Bs,
    float* __restrict__ Bd, float* __restrict__ Be,
    unsigned short* __restrict__ WsumT,
    const float* __restrict__ a2w, unsigned short* __restrict__ w2bf,
    const float* __restrict__ vnfc, const float* __restrict__ vw,
    const float* __restrict__ vb, const float* __restrict__ eab,
    const float* __restrict__ a1w, const float* __restrict__ a1b,
    const float* __restrict__ eaw, float* __restrict__ E1) {
    __shared__ float vr[128];
    __shared__ float sM1[512];
    __shared__ float sd1[128];
    int b = blockIdx.x, t = threadIdx.x;
    if (b < 5000) {             // node embedding
        int idx = b * 256 + t;
        int n = idx >> 7, c = idx & 127;
        const float* xr = x + (size_t)n * 8;
        float acc = nb[c];
#pragma unroll
        for (int k = 0; k < 8; k++) acc += xr[k] * nw[k * 128 + c];
        h[idx] = acc;
        hb[idx] = f2bf(acc);
        return;
    }
    if (b < 5665) {             // degree histogram
        int i = (b - 5000) * 256 + t;
        if (i < ET) {
            int d = (i < Ee) ? ei[Ee + i] : (i - Ee);
            atomicAdd(&hist[d], 1);
        }
        return;
    }
    if (b < 5677) {             // Bs/Bd/Be [L][128][4]
        int idx = (b - 5665) * 256 + t;
        if (idx >= LL * 128 * 4) return;
        int hh = idx & 3, k = (idx >> 2) & 127, l = idx >> 9;
        const float* lwp = glw  + (size_t)l * 65536 + k * 512 + hh * 128;
        const float* lep = glew + (size_t)l * 65536 + k * 512 + hh * 128;
        const float* sp = gas + l * 512 + hh * 128;
        const float* dp = gad + l * 512 + hh * 128;
        const float* ep = gae + l * 512 + hh * 128;
        float s1 = 0, s2 = 0, s3 = 0;
        for (int c = 0; c < 128; c++) {
            float lv = lwp[c];
            s1 += lv * sp[c];
            s2 += lv * dp[c];
            s3 += lep[c] * ep[c];
        }
        Bs[idx] = s1; Bd[idx] = s2; Be[idx] = s3;
        return;
    }
    if (b < 7213) {             // WsumT[l][c][kk] = bf16(0.25 * lw^T)
        int idx = (b - 5677) * 256 + t;
        int kk = idx & 511;
        int c = (idx >> 9) & 127;
        int l = idx >> 16;
        float v = 0.25f * glw[(size_t)l * 65536 + (size_t)(kk & 127) * 512 + (kk >> 7) * 128 + c];
        WsumT[(size_t)l * 65536 + (size_t)c * 512 + kk] = f2bf(v);
        return;
    }
    if (b < 7245) {             // w2 -> bf16 MFMA B-fragment order
        int idx = (b - 7213) * 256 + t;
        int j = idx & 7, lane = (idx >> 3) & 63, nt = (idx >> 9) & 3, ks = idx >> 11;
        int k = ks * 32 + ((lane >> 4) << 3) + j;
        int n = nt * 16 + (lane & 15);
        w2bf[idx] = f2bf(a2w[k * 64 + n]);
        return;
    }
    {                           // E1[128][8] = {M1[0..3][k], d1[k], 0,0,0}
        if (t < 128) {
            float a = vb[t];
#pragma unroll
            for (int k = 0; k < 6; k++) a += vnfc[k] * vw[k * 128 + t];
            vr[t] = a;
        }
        __syncthreads();
        if (t < 128) {
            float a = a1b[t];
            for (int k = 0; k < 128; k++) a += eab[k] * a1w[k * 128 + t];
            for (int k = 0; k < 128; k++) a += vr[k] * a1w[(128 + k) * 128 + t];
            sd1[t] = a;
        }
#pragma unroll
        for (int rr = 0; rr < 2; rr++) {
            int id = rr * 256 + t;
            int r = id >> 7, j = id & 127;
            float a = 0.f;
            for (int k = 0; k < 128; k++) a += eaw[r * 128 + k] * a1w[k * 128 + j];
            sM1[id] = a;
        }
        __syncthreads();
        if (t < 128) {
            E1[t * 8 + 0] = sM1[t];
            E1[t * 8 + 1] = sM1[128 + t];
            E1[t * 8 + 2] = sM1[256 + t];
            E1[t * 8 + 3] = sM1[384 + t];
            E1[t * 8 + 4] = sd1[t];
            E1[t * 8 + 5] = 0.f; E1[t * 8 + 6] = 0.f; E1[t * 8 + 7] = 0.f;
        }
    }
}

// ---- block 0: prefix scan over hist; block 1: PB/cB fold (needs Be from k_first) ----
__global__ __launch_bounds__(1024) void k_scan(
    const int* __restrict__ hist, int* __restrict__ seg, int* __restrict__ pos,
    const float* __restrict__ eaw, const float* __restrict__ eab,
    const float* __restrict__ Be, float* __restrict__ PB, float* __restrict__ cB) {
    __shared__ int wsums[16];
    __shared__ int carry_s;
    int t = threadIdx.x;
    if (blockIdx.x == 1) {      // PB[4][24], cB[24]
        if (t >= 24) return;
        int l = t >> 2, hh = t & 3;
        const float* bp = Be + l * 512 + hh;
        float s0 = 0, s1 = 0, s2 = 0, s3 = 0, sc = 0;
        for (int k = 0; k < 128; k++) {
            float bv = bp[k * 4];
            s0 += eaw[0 * 128 + k] * bv;
            s1 += eaw[1 * 128 + k] * bv;
            s2 += eaw[2 * 128 + k] * bv;
            s3 += eaw[3 * 128 + k] * bv;
            sc += eab[k] * bv;
        }
        PB[0 * 24 + t] = s0; PB[1 * 24 + t] = s1;
        PB[2 * 24 + t] = s2; PB[3 * 24 + t] = s3;
        cB[t] = sc;
        return;
    }
    int lane = t & 63, wid = t >> 6;
    if (t == 0) { carry_s = 0; seg[0] = 0; }
    __syncthreads();
    for (int base = 0; base < Nn; base += 1024) {
        int idx = base + t;
        int v = (idx < Nn) ? hist[idx] : 0;
        int sc = v;
#pragma unroll
        for (int d = 1; d < 64; d <<= 1) {
            int up = __shfl_up(sc, d);
            if (lane >= d) sc += up;
        }
        if (lane == 63) wsums[wid] = sc;
        __syncthreads();
        if (wid == 0) {
            int wv = (lane < 16) ? wsums[lane] : 0;
            int wsc = wv;
#pragma unroll
            for (int d = 1; d < 16; d <<= 1) {
                int up = __shfl_up(wsc, d);
                if (lane >= d) wsc += up;
            }
            if (lane < 16) wsums[lane] = wsc - wv;
        }
        __syncthreads();
        int carry = carry_s;
        int inc = sc + wsums[wid] + carry;
        if (idx < Nn) { seg[idx + 1] = inc; pos[idx] = inc - v; }
        __syncthreads();
        if (t == 1023) carry_s = inc;
        __syncthreads();
    }
}

// ---- edge gate MLP (MFMA) + inline scatter: claims dst-sorted slot, writes srcv/aleT ----
__global__ __launch_bounds__(256, 2) void k_edge(
    const float* __restrict__ ea, const float* __restrict__ E1,
    const unsigned short* __restrict__ w2bf,
    const float* __restrict__ a2b, const float* __restrict__ a3w,
    const float* __restrict__ a3b,
    const float* __restrict__ PB, const float* __restrict__ cB,
    const int* __restrict__ ei, int* __restrict__ pos, int* __restrict__ srcv,
    float* __restrict__ aleT, float* __restrict__ gsum) {
    __shared__ float4 sM[128];     // swizzled: row k stored at k ^ ((k>>3)&3)
    __shared__ float sD[128];
    __shared__ float4 sevs[256];
    __shared__ float gsh[256];
    __shared__ float sgsum[5];
    int t = threadIdx.x;
    int lane = t & 63;
    int wid = t >> 6;
    int c = lane & 15, q = lane >> 4;
    int eb0 = blockIdx.x * 256;

    int my_src = ei[eb0 + t];
    int my_dst = ei[Ee + eb0 + t];
    sevs[t] = *(const float4*)(ea + (size_t)(eb0 + t) * 4);
    if (t < 128) {
        int slot = t ^ ((t >> 3) & 3);
        sM[slot] = *(const float4*)(E1 + t * 8);
        sD[t] = E1[t * 8 + 4];
    }
    if (t < 5) sgsum[t] = 0.f;
    __syncthreads();

    float4 ev4[4];
#pragma unroll
    for (int mt = 0; mt < 4; mt++) ev4[mt] = sevs[(wid * 4 + mt) * 16 + c];

    // layer 1: hidden1 -> bf16 A-fragments
    v8s av[4][4];
#pragma unroll
    for (int ks = 0; ks < 4; ks++) {
        float4 mr[8]; float dr[8];
#pragma unroll
        for (int j = 0; j < 8; j++) {
            int k = ks * 32 + q * 8 + j;
            mr[j] = sM[k ^ q];
            dr[j] = sD[k];
        }
#pragma unroll
        for (int mt = 0; mt < 4; mt++) {
            float4 ev = ev4[mt];
            v8s a;
#pragma unroll
            for (int j = 0; j < 8; j++) {
                float xv = fmaxf(dr[j] + ev.x * mr[j].x + ev.y * mr[j].y
                                       + ev.z * mr[j].z + ev.w * mr[j].w, 0.f);
                a[j] = (short)f2bf(xv);
            }
            av[mt][ks] = a;
        }
    }

    // layer 2: MFMA, bias in C-init
    v4f acc[4][4];
#pragma unroll
    for (int nt = 0; nt < 4; nt++) {
        float bb = a2b[nt * 16 + c];
#pragma unroll
        for (int mt = 0; mt < 4; mt++) acc[mt][nt] = (v4f){bb, bb, bb, bb};
    }
#pragma unroll
    for (int nt = 0; nt < 4; nt++) {
#pragma unroll
        for (int ks = 0; ks < 4; ks++) {
            v8s bfr = *(const v8s*)(w2bf + ((size_t)(ks * 4 + nt) * 64 + lane) * 8);
#pragma unroll
            for (int mt = 0; mt < 4; mt++)
                acc[mt][nt] = __builtin_amdgcn_mfma_f32_16x16x32_bf16(av[mt][ks], bfr, acc[mt][nt], 0, 0, 0);
        }
    }

    // layer 3 + sigmoid
    float a3r[4];
#pragma unroll
    for (int nt = 0; nt < 4; nt++) a3r[nt] = a3w[nt * 16 + c];
    float a3b0 = a3b[0];
#pragma unroll
    for (int mt = 0; mt < 4; mt++) {
#pragma unroll
        for (int r = 0; r < 4; r++) {
            float s = 0.f;
#pragma unroll
            for (int nt = 0; nt < 4; nt++) s += fmaxf(acc[mt][nt][r], 0.f) * a3r[nt];
            s += __shfl_xor(s, 1); s += __shfl_xor(s, 2);
            s += __shfl_xor(s, 4); s += __shfl_xor(s, 8);
            if (c == 0) gsh[(wid * 4 + mt) * 16 + q * 4 + r] = 1.f / (1.f + __expf(-(s + a3b0)));
        }
    }
    __syncthreads();

    // per-edge epilogue
    float g = gsh[t];
    float4 evv = sevs[t];
    float v0 = g, v1 = g * evv.x, v2 = g * evv.y, v3 = g * evv.z, v4 = g * evv.w;
#pragma unroll
    for (int d = 32; d > 0; d >>= 1) {
        v0 += __shfl_down(v0, d); v1 += __shfl_down(v1, d); v2 += __shfl_down(v2, d);
        v3 += __shfl_down(v3, d); v4 += __shfl_down(v4, d);
    }
    if (lane == 0) {
        atomicAdd(&sgsum[0], v0); atomicAdd(&sgsum[1], v1); atomicAdd(&sgsum[2], v2);
        atomicAdd(&sgsum[3], v3); atomicAdd(&sgsum[4], v4);
    }
    __syncthreads();
    if (t < 5) atomicAdd(&gsum[t], sgsum[t]);
    int slot = atomicAdd(&pos[my_dst], 1);
    srcv[slot] = my_src;
#pragma unroll
    for (int i4 = 0; i4 < 6; i4++) {
        float4 cc = *(const float4*)(cB + i4 * 4);
        float4 p0 = *(const float4*)(PB + 0 * 24 + i4 * 4);
        float4 p1 = *(const float4*)(PB + 1 * 24 + i4 * 4);
        float4 p2 = *(const float4*)(PB + 2 * 24 + i4 * 4);
        float4 p3 = *(const float4*)(PB + 3 * 24 + i4 * 4);
        float4 o;
        o.x = g * (cc.x + evv.x * p0.x + evv.y * p1.x + evv.z * p2.x + evv.w * p3.x);
        o.y = g * (cc.y + evv.x * p0.y + evv.y * p1.y + evv.z * p2.y + evv.w * p3.y);
        o.z = g * (cc.z + evv.x * p0.z + evv.y * p1.z + evv.z * p2.z + evv.w * p3.z);
        o.w = g * (cc.w + evv.x * p0.w + evv.y * p1.w + evv.z * p2.w + evv.w * p3.w);
        *(float4*)(aleT + (size_t)i4 * ET * 4 + (size_t)slot * 4) = o;
    }
}

// ---- fused: als/ald layer0 (blocks 0..312) + per-node self-loop scatter+fill (313..352) ----
__global__ __launch_bounds__(256) void k_abfill(
    const float* __restrict__ h, const float* __restrict__ Bs_l,
    const float* __restrict__ Bd_l, float* __restrict__ als, float* __restrict__ ald,
    int* __restrict__ pos, int* __restrict__ srcv, const float* __restrict__ gsum,
    const float* __restrict__ PB, const float* __restrict__ cB,
    float* __restrict__ aleT) {
    int b = blockIdx.x, t = threadIdx.x;
    if (b < 313) {
        int idx = b * 256 + t;
        if (idx >= Nn * 8) return;
        int n = idx >> 3, slot = idx & 7;
        const float* B = (slot < 4) ? Bs_l : Bd_l;
        int hh = slot & 3;
        const float4* hr = (const float4*)(h + (size_t)n * 128);
        float s = 0.f;
#pragma unroll 8
        for (int kb = 0; kb < 32; kb++) {
            float4 hv = hr[kb];
            s += hv.x * B[(4 * kb + 0) * 4 + hh] + hv.y * B[(4 * kb + 1) * 4 + hh]
               + hv.z * B[(4 * kb + 2) * 4 + hh] + hv.w * B[(4 * kb + 3) * 4 + hh];
        }
        if (slot < 4) als[n * 4 + hh] = s;
        else          ald[n * 4 + hh] = s;
        return;
    }
    {
        int j = (b - 313) * 256 + t;    // node index
        if (j >= Nn) return;
        int slot = atomicAdd(&pos[j], 1);
        srcv[slot] = j;
        float g0 = gsum[0], g1 = gsum[1], g2 = gsum[2], g3 = gsum[3], g4 = gsum[4];
#pragma unroll
        for (int l = 0; l < LL; l++) {
            float4 cc = *(const float4*)(cB + l * 4);
            float4 p0 = *(const float4*)(PB + 0 * 24 + l * 4);
            float4 p1 = *(const float4*)(PB + 1 * 24 + l * 4);
            float4 p2 = *(const float4*)(PB + 2 * 24 + l * 4);
            float4 p3 = *(const float4*)(PB + 3 * 24 + l * 4);
            float4 o;
            o.x = (g0 * cc.x + g1 * p0.x + g2 * p1.x + g3 * p2.x + g4 * p3.x) * (1.0f / Ee);
            o.y = (g0 * cc.y + g1 * p0.y + g2 * p1.y + g3 * p2.y + g4 * p3.y) * (1.0f / Ee);
            o.z = (g0 * cc.z + g1 * p0.z + g2 * p1.z + g3 * p2.z + g4 * p3.z) * (1.0f / Ee);
            o.w = (g0 * cc.w + g1 * p0.w + g2 * p1.w + g3 * p2.w + g4 * p3.w) * (1.0f / Ee);
            *(float4*)(aleT + (size_t)l * ET * 4 + (size_t)slot * 4) = o;
        }
    }
}

// ---- per-layer agg: single-pass no-max softmax; 2 waves/node; 4-edge grouped loads ----
__global__ __launch_bounds__(256) void k_agg3(
    const int* __restrict__ srcv, const int* __restrict__ seg,
    const float* __restrict__ als, const float* __restrict__ ald,
    const float* __restrict__ aleS_l,
    const unsigned short* __restrict__ hb, unsigned short* __restrict__ aggb) {
    __shared__ float part[2][512];
    __shared__ float pden[2][4];
    int t = threadIdx.x;
    int lane = t & 63;
    int wv = (t >> 6) & 1;
    int w = t >> 7;
    int n = blockIdx.x * 2 + w;
    int start = seg[n], end = seg[n + 1];
    int deg = end - start;
    int half = (deg + 1) >> 1;
    int s0 = start + wv * half;
    int e0 = wv ? end : start + half;
    int hp = lane >> 4;
    int cch = (lane & 15) * 8;
    float aldh = ald[n * 4 + hp];
    float den = 0.f;
    float4 acc0 = make_float4(0.f, 0.f, 0.f, 0.f);
    float4 acc1 = make_float4(0.f, 0.f, 0.f, 0.f);
    int i = s0;
    for (; i + 4 <= e0; i += 4) {
        int sa = srcv[i], sb = srcv[i + 1], sc = srcv[i + 2], sd = srcv[i + 3];
        float ala = aleS_l[(size_t)(i + 0) * 4 + hp];
        float alb = aleS_l[(size_t)(i + 1) * 4 + hp];
        float alc = aleS_l[(size_t)(i + 2) * 4 + hp];
        float ald_ = aleS_l[(size_t)(i + 3) * 4 + hp];
        float asa = als[sa * 4 + hp], asb = als[sb * 4 + hp];
        float asc = als[sc * 4 + hp], asd = als[sd * 4 + hp];
        uint4 ua = *(const uint4*)(hb + (size_t)sa * 128 + cch);
        uint4 ub = *(const uint4*)(hb + (size_t)sb * 128 + cch);
        uint4 uc = *(const uint4*)(hb + (size_t)sc * 128 + cch);
        uint4 ud = *(const uint4*)(hb + (size_t)sd * 128 + cch);
        float ava = asa + aldh + ala; ava = ava > 0.f ? ava : 0.2f * ava;
        float avb = asb + aldh + alb; avb = avb > 0.f ? avb : 0.2f * avb;
        float avc = asc + aldh + alc; avc = avc > 0.f ? avc : 0.2f * avc;
        float avd = asd + aldh + ald_; avd = avd > 0.f ? avd : 0.2f * avd;
        float ea = __expf(fminf(ava, 60.f));
        float eb = __expf(fminf(avb, 60.f));
        float ec = __expf(fminf(avc, 60.f));
        float ed = __expf(fminf(avd, 60.f));
        den += (ea + eb) + (ec + ed);
        acc0.x += (ea * bflo(ua.x) + eb * bflo(ub.x)) + (ec * bflo(uc.x) + ed * bflo(ud.x));
        acc0.y += (ea * bfhi(ua.x) + eb * bfhi(ub.x)) + (ec * bfhi(uc.x) + ed * bfhi(ud.x));
        acc0.z += (ea * bflo(ua.y) + eb * bflo(ub.y)) + (ec * bflo(uc.y) + ed * bflo(ud.y));
        acc0.w += (ea * bfhi(ua.y) + eb * bfhi(ub.y)) + (ec * bfhi(uc.y) + ed * bfhi(ud.y));
        acc1.x += (ea * bflo(ua.z) + eb * bflo(ub.z)) + (ec * bflo(uc.z) + ed * bflo(ud.z));
        acc1.y += (ea * bfhi(ua.z) + eb * bfhi(ub.z)) + (ec * bfhi(uc.z) + ed * bfhi(ud.z));
        acc1.z += (ea * bflo(ua.w) + eb * bflo(ub.w)) + (ec * bflo(uc.w) + ed * bflo(ud.w));
        acc1.w += (ea * bfhi(ua.w) + eb * bfhi(ub.w)) + (ec * bfhi(uc.w) + ed * bfhi(ud.w));
    }
    for (; i < e0; i++) {
        int sa = srcv[i];
        float ala = aleS_l[(size_t)i * 4 + hp];
        float ava = als[sa * 4 + hp] + aldh + ala;
        ava = ava > 0.f ? ava : 0.2f * ava;
        float ea = __expf(fminf(ava, 60.f));
        den += ea;
        uint4 ua = *(const uint4*)(hb + (size_t)sa * 128 + cch);
        acc0.x += ea * bflo(ua.x); acc0.y += ea * bfhi(ua.x);
        acc0.z += ea * bflo(ua.y); acc0.w += ea * bfhi(ua.y);
        acc1.x += ea * bflo(ua.z); acc1.y += ea * bfhi(ua.z);
        acc1.z += ea * bflo(ua.w); acc1.w += ea * bfhi(ua.w);
    }
    if (wv == 1) {
        *(float4*)&part[w][lane * 8] = acc0;
        *(float4*)&part[w][lane * 8 + 4] = acc1;
        if ((lane & 15) == 0) pden[w][hp] = den;
    }
    __syncthreads();
    if (wv == 0) {
        float4 p0 = *(const float4*)&part[w][lane * 8];
        float4 p1 = *(const float4*)&part[w][lane * 8 + 4];
        float inv2 = 1.f / (den + pden[w][hp] + 1e-16f);
        acc0.x = (acc0.x + p0.x) * inv2; acc0.y = (acc0.y + p0.y) * inv2;
        acc0.z = (acc0.z + p0.z) * inv2; acc0.w = (acc0.w + p0.w) * inv2;
        acc1.x = (acc1.x + p1.x) * inv2; acc1.y = (acc1.y + p1.y) * inv2;
        acc1.z = (acc1.z + p1.z) * inv2; acc1.w = (acc1.w + p1.w) * inv2;
        ushort4 q0, q1;
        q0.x = f2bf(acc0.x); q0.y = f2bf(acc0.y); q0.z = f2bf(acc0.z); q0.w = f2bf(acc0.w);
        q1.x = f2bf(acc1.x); q1.y = f2bf(acc1.y); q1.z = f2bf(acc1.z); q1.w = f2bf(acc1.w);
        *(ushort4*)(aggb + (size_t)n * 512 + lane * 8) = q0;
        *(ushort4*)(aggb + (size_t)n * 512 + lane * 8 + 4) = q1;
    }
}

// ---- per-layer: h_new = LN(relu(aggcat @ Wsum + gbias) + h); + next-layer als/ald ----
__global__ __launch_bounds__(256) void k_post(
    const unsigned short* __restrict__ aggb, const unsigned short* __restrict__ WsumT_l,
    const float* __restrict__ gbias, const float* __restrict__ lnsc,
    const float* __restrict__ lnbi, float* __restrict__ h,
    unsigned short* __restrict__ hb, const float* __restrict__ Bs_n,
    const float* __restrict__ Bd_n, float* __restrict__ als, float* __restrict__ ald) {
    int t = threadIdx.x;
    int lane = t & 63, w = t >> 6;
    int n0 = (blockIdx.x * 4 + w) * 16;
    if (n0 >= Nn) return;
    int m = lane & 15, q = lane >> 4;
    v4f acc[8];
#pragma unroll
    for (int nt = 0; nt < 8; nt++) acc[nt] = (v4f){0.f, 0.f, 0.f, 0.f};
    const unsigned short* arow = aggb + (size_t)(n0 + m) * 512 + q * 8;
#pragma unroll 4
    for (int ks = 0; ks < 16; ks++) {
        v8s fa = *(const v8s*)(arow + ks * 32);
#pragma unroll
        for (int nt = 0; nt < 8; nt++) {
            int col = nt * 16 + m;
            v8s fb = *(const v8s*)(WsumT_l + (size_t)col * 512 + ks * 32 + q * 8);
            acc[nt] = __builtin_amdgcn_mfma_f32_16x16x32_bf16(fa, fb, acc[nt], 0, 0, 0);
        }
    }
    float v[8][4];
    float s1[4] = {0.f, 0.f, 0.f, 0.f}, s2[4] = {0.f, 0.f, 0.f, 0.f};
#pragma unroll
    for (int nt = 0; nt < 8; nt++) {
        int col = nt * 16 + m;
        float b = gbias[col];
#pragma unroll
        for (int r = 0; r < 4; r++) {
            int row = n0 + q * 4 + r;
            float val = h[(size_t)row * 128 + col] + fmaxf(acc[nt][r] + b, 0.f);
            v[nt][r] = val;
            s1[r] += val; s2[r] += val * val;
        }
    }
#pragma unroll
    for (int d = 1; d <= 8; d <<= 1) {
#pragma unroll
        for (int r = 0; r < 4; r++) {
            s1[r] += __shfl_xor(s1[r], d);
            s2[r] += __shfl_xor(s2[r], d);
        }
    }
    float o8[8][4];
#pragma unroll
    for (int r = 0; r < 4; r++) {
        float mean = s1[r] * (1.f / 128.f);
        float var = s2[r] * (1.f / 128.f) - mean * mean;
        float rinv = rsqrtf(var + 1e-5f);
        int row = n0 + q * 4 + r;
#pragma unroll
        for (int nt = 0; nt < 8; nt++) {
            int col = nt * 16 + m;
            float o = (v[nt][r] - mean) * rinv * lnsc[col] + lnbi[col];
            o8[nt][r] = o;
            h[(size_t)row * 128 + col] = o;
            hb[(size_t)row * 128 + col] = f2bf(o);
        }
    }
    float sal[4][4], sad[4][4];
#pragma unroll
    for (int r = 0; r < 4; r++) {
#pragma unroll
        for (int hh = 0; hh < 4; hh++) { sal[r][hh] = 0.f; sad[r][hh] = 0.f; }
    }
#pragma unroll
    for (int nt = 0; nt < 8; nt++) {
        int col = nt * 16 + m;
        float4 bs = *(const float4*)(Bs_n + col * 4);
        float4 bd = *(const float4*)(Bd_n + col * 4);
#pragma unroll
        for (int r = 0; r < 4; r++) {
            float o = o8[nt][r];
            sal[r][0] += o * bs.x; sal[r][1] += o * bs.y;
            sal[r][2] += o * bs.z; sal[r][3] += o * bs.w;
            sad[r][0] += o * bd.x; sad[r][1] += o * bd.y;
            sad[r][2] += o * bd.z; sad[r][3] += o * bd.w;
        }
    }
#pragma unroll
    for (int d = 1; d <= 8; d <<= 1) {
#pragma unroll
        for (int r = 0; r < 4; r++) {
#pragma unroll
            for (int hh = 0; hh < 4; hh++) {
                sal[r][hh] += __shfl_xor(sal[r][hh], d);
                sad[r][hh] += __shfl_xor(sad[r][hh], d);
            }
        }
    }
    if (m < 8) {
        int hh = m & 3;
#pragma unroll
        for (int r = 0; r < 4; r++) {
            int row = n0 + q * 4 + r;
            float va = (hh == 0) ? sal[r][0] : (hh == 1) ? sal[r][1] : (hh == 2) ? sal[r][2] : sal[r][3];
            float vd = (hh == 0) ? sad[r][0] : (hh == 1) ? sad[r][1] : (hh == 2) ? sad[r][2] : sad[r][3];
            if (m < 4) als[row * 4 + hh] = va;
            else       ald[row * 4 + hh] = vd;
        }
    }
}

// ---------------- output projection ----------------
__global__ __launch_bounds__(256) void k_out(
    const float* __restrict__ h, const float* __restrict__ ow,
    const float* __restrict__ ob, float* __restrict__ out) {
    __shared__ float4 hs4[8][32];
    int t = threadIdx.x;
    int n0 = blockIdx.x * 8;
    if (t < 256) {
        int i = t >> 5, kb = t & 31;
        hs4[i][kb] = *(const float4*)(h + (size_t)(n0 + i) * 128 + 4 * kb);
    }
    __syncthreads();
    float acc[8] = {0, 0, 0, 0, 0, 0, 0, 0};
    for (int kb = 0; kb < 32; kb++) {
        float w0 = ow[(4 * kb + 0) * 256 + t];
        float w1 = ow[(4 * kb + 1) * 256 + t];
        float w2 = ow[(4 * kb + 2) * 256 + t];
        float w3 = ow[(4 * kb + 3) * 256 + t];
#pragma unroll
        for (int i = 0; i < 8; i++) {
            float4 hv = hs4[i][kb];
            acc[i] += hv.x * w0 + hv.y * w1 + hv.z * w2 + hv.w * w3;
        }
    }
    float b = ob[t];
#pragma unroll
    for (int i = 0; i < 8; i++) out[(size_t)(n0 + i) * 256 + t] = acc[i] + b;
}

extern "C" void kernel_launch(void* const* d_in, const int* in_sizes, int n_in,
                              void* d_out, int out_size, void* d_ws, size_t ws_size,
                              hipStream_t stream) {
    const float* x    = (const float*)d_in[0];
    const int*   ei   = (const int*)d_in[1];
    const float* ea   = (const float*)d_in[2];
    const float* vnfc = (const float*)d_in[3];
    const float* nw   = (const float*)d_in[4];
    const float* nb   = (const float*)d_in[5];
    const float* eaw  = (const float*)d_in[6];
    const float* eab  = (const float*)d_in[7];
    const float* vw   = (const float*)d_in[8];
    const float* vb   = (const float*)d_in[9];
    const float* a1w  = (const float*)d_in[10];
    const float* a1b  = (const float*)d_in[11];
    const float* a2w  = (const float*)d_in[12];
    const float* a2b  = (const float*)d_in[13];
    const float* a3w  = (const float*)d_in[14];
    const float* a3b  = (const float*)d_in[15];
    const float* glw  = (const float*)d_in[16];
    const float* gas  = (const float*)d_in[17];
    const float* gad  = (const float*)d_in[18];
    const float* glew = (const float*)d_in[19];
    const float* gae  = (const float*)d_in[20];
    const float* gb   = (const float*)d_in[21];
    const float* lnsc = (const float*)d_in[22];
    const float* lnbi = (const float*)d_in[23];
    const float* ow   = (const float*)d_in[24];
    const float* ob   = (const float*)d_in[25];
    float* out = (float*)d_out;

    char* w = (char*)d_ws;
    size_t o = 0;
    auto allocf = [&](size_t cnt) { float* p = (float*)(w + o); o += ((cnt * 4 + 255) / 256) * 256; return p; };
    auto alloci = [&](size_t cnt) { int* p = (int*)(w + o); o += ((cnt * 4 + 255) / 256) * 256; return p; };
    auto allocu = [&](size_t cnt) { unsigned short* p = (unsigned short*)(w + o); o += ((cnt * 2 + 255) / 256) * 256; return p; };
    // hist + gsum adjacent -> single memset
    int* hist     = alloci(Nn);
    float* gsum   = allocf(8);
    float* h      = allocf((size_t)Nn * 128);
    unsigned short* hb    = allocu((size_t)Nn * 128);
    unsigned short* aggb  = allocu((size_t)Nn * 512);
    unsigned short* WsumT = allocu((size_t)LL * 128 * 512);
    unsigned short* w2bf  = allocu(8192);
    float* als    = allocf((size_t)Nn * 4);
    float* ald    = allocf((size_t)Nn * 4);
    float* aleT   = allocf((size_t)LL * ET * 4);   // dst-sorted slots
    float* Bs     = allocf(3072);
    float* Bd     = allocf(3072);
    float* Be     = allocf(3072);
    float* E1     = allocf(1024);
    float* PB     = allocf(96);
    float* cB     = allocf(24);
    int* seg      = alloci(Nn + 1);
    int* pos      = alloci(Nn);
    int* srcv     = alloci(ET);

    // one memset covers hist (40000B + pad) and gsum (32B)
    hipMemsetAsync(hist, 0, ((size_t)Nn * 4 + 255) / 256 * 256 + 256, stream);

    k_first<<<7246, 256, 0, stream>>>(x, nw, nb, h, hb, ei, hist,
                                      glw, gas, gad, glew, gae, Bs, Bd, Be,
                                      WsumT, a2w, w2bf, vnfc, vw, vb, eab,
                                      a1w, a1b, eaw, E1);
    k_scan<<<2, 1024, 0, stream>>>(hist, seg, pos, eaw, eab, Be, PB, cB);
    k_edge<<<Ee / 256, 256, 0, stream>>>(ea, E1, w2bf, a2b, a3w, a3b, PB, cB,
                                         ei, pos, srcv, aleT, gsum);
    k_abfill<<<353, 256, 0, stream>>>(h, Bs, Bd, als, ald, pos, srcv, gsum, PB, cB, aleT);
    for (int l = 0; l < LL; l++) {
        int ln = (l + 1) % LL;
        k_agg3<<<Nn / 2, 256, 0, stream>>>(srcv, seg, als, ald,
                                           aleT + (size_t)l * ET * 4, hb, aggb);
        k_post<<<(625 + 3) / 4, 256, 0, stream>>>(aggb, WsumT + (size_t)l * 65536,
                                                  gb + l * 128, lnsc + l * 128, lnbi + l * 128,
                                                  h, hb, Bs + ln * 512, Bd + ln * 512, als, ald);
    }
    k_out<<<Nn / 8, 256, 0, stream>>>(h, ow, ob, out);
}

// Round 6
// 466.093 us; speedup vs baseline: 1.1537x; 1.0214x over previous
//
#include <hip/hip_runtime.h>
#include <hip/hip_bf16.h>
#include <math.h>

#define Nn 10000
#define Ee 160000
#define LL 6

typedef short v8s __attribute__((ext_vector_type(8)));
typedef float v4f __attribute__((ext_vector_type(4)));

__device__ __forceinline__ unsigned short f2bf(float v) {
    unsigned int b = __float_as_uint(v);
    b += 0x7fffu + ((b >> 16) & 1u);   // RNE
    return (unsigned short)(b >> 16);
}
__device__ __forceinline__ float bflo(unsigned int u) { return __uint_as_float(u << 16); }
__device__ __forceinline__ float bfhi(unsigned int u) { return __uint_as_float(u & 0xffff0000u); }

// ---- fused: embed(0..4999) + hist(5000..5624) + bmat(5625..5636) + wsum(5637..7172)
//      + w2b(7173..7204) + owbT(7205..7332) + small/E1(7333) ----
__global__ __launch_bounds__(256) void k_first(
    const float* __restrict__ x, const float* __restrict__ nw,
    const float* __restrict__ nb, float* __restrict__ h, unsigned short* __restrict__ hb,
    const int* __restrict__ ei, int* __restrict__ hist,
    const float* __restrict__ glw, const float* __restrict__ gas,
    const float* __restrict__ gad, const float* __restrict__ glew,
    const float* __restrict__ gae, float* __restrict__ Bs,
    float* __restrict__ Bd, float* __restrict__ Be,
    unsigned short* __restrict__ WsumT,
    const float* __restrict__ a2w, unsigned short* __restrict__ w2bf,
    const float* __restrict__ ow, unsigned short* __restrict__ owbT,
    const float* __restrict__ vnfc, const float* __restrict__ vw,
    const float* __restrict__ vb, const float* __restrict__ eab,
    const float* __restrict__ a1w, const float* __restrict__ a1b,
    const float* __restrict__ eaw, float* __restrict__ E1) {
    __shared__ float vr[128];
    __shared__ float sM1[512];
    __shared__ float sd1[128];
    int b = blockIdx.x, t = threadIdx.x;
    if (b < 5000) {             // node embedding
        int idx = b * 256 + t;
        int n = idx >> 7, c = idx & 127;
        const float* xr = x + (size_t)n * 8;
        float acc = nb[c];
#pragma unroll
        for (int k = 0; k < 8; k++) acc += xr[k] * nw[k * 128 + c];
        h[idx] = acc;
        hb[idx] = f2bf(acc);
        return;
    }
    if (b < 5625) {             // degree histogram over real edges only
        int i = (b - 5000) * 256 + t;
        atomicAdd(&hist[ei[Ee + i]], 1);
        return;
    }
    if (b < 5637) {             // Bs/Bd/Be [L][128][4]
        int idx = (b - 5625) * 256 + t;
        if (idx >= LL * 128 * 4) return;
        int hh = idx & 3, k = (idx >> 2) & 127, l = idx >> 9;
        const float* lwp = glw  + (size_t)l * 65536 + k * 512 + hh * 128;
        const float* lep = glew + (size_t)l * 65536 + k * 512 + hh * 128;
        const float* sp = gas + l * 512 + hh * 128;
        const float* dp = gad + l * 512 + hh * 128;
        const float* ep = gae + l * 512 + hh * 128;
        float s1 = 0, s2 = 0, s3 = 0;
        for (int c = 0; c < 128; c++) {
            float lv = lwp[c];
            s1 += lv * sp[c];
            s2 += lv * dp[c];
            s3 += lep[c] * ep[c];
        }
        Bs[idx] = s1; Bd[idx] = s2; Be[idx] = s3;
        return;
    }
    if (b < 7173) {             // WsumT[l][c][kk] = bf16(0.25 * lw^T)
        int idx = (b - 5637) * 256 + t;
        int kk = idx & 511;
        int c = (idx >> 9) & 127;
        int l = idx >> 16;
        float v = 0.25f * glw[(size_t)l * 65536 + (size_t)(kk & 127) * 512 + (kk >> 7) * 128 + c];
        WsumT[(size_t)l * 65536 + (size_t)c * 512 + kk] = f2bf(v);
        return;
    }
    if (b < 7205) {             // w2 -> bf16 MFMA B-fragment order
        int idx = (b - 7173) * 256 + t;
        int j = idx & 7, lane = (idx >> 3) & 63, nt = (idx >> 9) & 3, ks = idx >> 11;
        int k = ks * 32 + ((lane >> 4) << 3) + j;
        int n = nt * 16 + (lane & 15);
        w2bf[idx] = f2bf(a2w[k * 64 + n]);
        return;
    }
    if (b < 7333) {             // owbT[c][k] = bf16(ow[k][c]), c<256, k<128
        int idx = (b - 7205) * 256 + t;
        int col = idx >> 7, kk = idx & 127;
        owbT[idx] = f2bf(ow[kk * 256 + col]);
        return;
    }
    {                           // E1[128][8] = {M1[0..3][k], d1[k], 0,0,0}
        if (t < 128) {
            float a = vb[t];
#pragma unroll
            for (int k = 0; k < 6; k++) a += vnfc[k] * vw[k * 128 + t];
            vr[t] = a;
        }
        __syncthreads();
        if (t < 128) {
            float a = a1b[t];
            for (int k = 0; k < 128; k++) a += eab[k] * a1w[k * 128 + t];
            for (int k = 0; k < 128; k++) a += vr[k] * a1w[(128 + k) * 128 + t];
            sd1[t] = a;
        }
#pragma unroll
        for (int rr = 0; rr < 2; rr++) {
            int id = rr * 256 + t;
            int r = id >> 7, j = id & 127;
            float a = 0.f;
            for (int k = 0; k < 128; k++) a += eaw[r * 128 + k] * a1w[k * 128 + j];
            sM1[id] = a;
        }
        __syncthreads();
        if (t < 128) {
            E1[t * 8 + 0] = sM1[t];
            E1[t * 8 + 1] = sM1[128 + t];
            E1[t * 8 + 2] = sM1[256 + t];
            E1[t * 8 + 3] = sM1[384 + t];
            E1[t * 8 + 4] = sd1[t];
            E1[t * 8 + 5] = 0.f; E1[t * 8 + 6] = 0.f; E1[t * 8 + 7] = 0.f;
        }
    }
}

// ---- block 0: prefix scan over hist; block 1: PB/cB fold (needs Be from k_first) ----
__global__ __launch_bounds__(1024) void k_scan(
    const int* __restrict__ hist, int* __restrict__ seg, int* __restrict__ pos,
    const float* __restrict__ eaw, const float* __restrict__ eab,
    const float* __restrict__ Be, float* __restrict__ PB, float* __restrict__ cB) {
    __shared__ int wsums[16];
    __shared__ int carry_s;
    int t = threadIdx.x;
    if (blockIdx.x == 1) {      // PB[4][24], cB[24]
        if (t >= 24) return;
        int l = t >> 2, hh = t & 3;
        const float* bp = Be + l * 512 + hh;
        float s0 = 0, s1 = 0, s2 = 0, s3 = 0, sc = 0;
        for (int k = 0; k < 128; k++) {
            float bv = bp[k * 4];
            s0 += eaw[0 * 128 + k] * bv;
            s1 += eaw[1 * 128 + k] * bv;
            s2 += eaw[2 * 128 + k] * bv;
            s3 += eaw[3 * 128 + k] * bv;
            sc += eab[k] * bv;
        }
        PB[0 * 24 + t] = s0; PB[1 * 24 + t] = s1;
        PB[2 * 24 + t] = s2; PB[3 * 24 + t] = s3;
        cB[t] = sc;
        return;
    }
    int lane = t & 63, wid = t >> 6;
    if (t == 0) { carry_s = 0; seg[0] = 0; }
    __syncthreads();
    for (int base = 0; base < Nn; base += 1024) {
        int idx = base + t;
        int v = (idx < Nn) ? hist[idx] : 0;
        int sc = v;
#pragma unroll
        for (int d = 1; d < 64; d <<= 1) {
            int up = __shfl_up(sc, d);
            if (lane >= d) sc += up;
        }
        if (lane == 63) wsums[wid] = sc;
        __syncthreads();
        if (wid == 0) {
            int wv = (lane < 16) ? wsums[lane] : 0;
            int wsc = wv;
#pragma unroll
            for (int d = 1; d < 16; d <<= 1) {
                int up = __shfl_up(wsc, d);
                if (lane >= d) wsc += up;
            }
            if (lane < 16) wsums[lane] = wsc - wv;
        }
        __syncthreads();
        int carry = carry_s;
        int inc = sc + wsums[wid] + carry;
        if (idx < Nn) { seg[idx + 1] = inc; pos[idx] = inc - v; }
        __syncthreads();
        if (t == 1023) carry_s = inc;
        __syncthreads();
    }
}

// ---- edge gate MLP (MFMA) + inline scatter (blocks 0..624); als/ald from h (625..937) ----
__global__ __launch_bounds__(256, 2) void k_edge(
    const float* __restrict__ ea, const float* __restrict__ E1,
    const unsigned short* __restrict__ w2bf,
    const float* __restrict__ a2b, const float* __restrict__ a3w,
    const float* __restrict__ a3b,
    const float* __restrict__ PB, const float* __restrict__ cB,
    const int* __restrict__ ei, int* __restrict__ pos, int* __restrict__ srcv,
    float* __restrict__ aleT, float* __restrict__ gsum,
    const float* __restrict__ h, const float* __restrict__ Bs,
    const float* __restrict__ Bd, float* __restrict__ als, float* __restrict__ ald) {
    __shared__ float4 sM[128];     // swizzled: row k stored at k ^ ((k>>3)&3)
    __shared__ float sD[128];
    __shared__ float4 sevs[256];
    __shared__ float gsh[256];
    __shared__ float sgsum[5];
    int t = threadIdx.x;
    int b = blockIdx.x;
    if (b >= 625) {             // layer-0 als/ald = h @ Bs/Bd
        int idx = (b - 625) * 256 + t;
        if (idx >= Nn * 8) return;
        int n = idx >> 3, slot = idx & 7;
        const float* B = (slot < 4) ? Bs : Bd;
        int hh = slot & 3;
        const float4* hr = (const float4*)(h + (size_t)n * 128);
        float s = 0.f;
#pragma unroll 8
        for (int kb = 0; kb < 32; kb++) {
            float4 hv = hr[kb];
            s += hv.x * B[(4 * kb + 0) * 4 + hh] + hv.y * B[(4 * kb + 1) * 4 + hh]
               + hv.z * B[(4 * kb + 2) * 4 + hh] + hv.w * B[(4 * kb + 3) * 4 + hh];
        }
        if (slot < 4) als[n * 4 + hh] = s;
        else          ald[n * 4 + hh] = s;
        return;
    }
    int lane = t & 63;
    int wid = t >> 6;
    int c = lane & 15, q = lane >> 4;
    int eb0 = b * 256;

    int my_src = ei[eb0 + t];
    int my_dst = ei[Ee + eb0 + t];
    sevs[t] = *(const float4*)(ea + (size_t)(eb0 + t) * 4);
    if (t < 128) {
        int slot = t ^ ((t >> 3) & 3);
        sM[slot] = *(const float4*)(E1 + t * 8);
        sD[t] = E1[t * 8 + 4];
    }
    if (t < 5) sgsum[t] = 0.f;
    __syncthreads();

    float4 ev4[4];
#pragma unroll
    for (int mt = 0; mt < 4; mt++) ev4[mt] = sevs[(wid * 4 + mt) * 16 + c];

    // layer 1: hidden1 -> bf16 A-fragments
    v8s av[4][4];
#pragma unroll
    for (int ks = 0; ks < 4; ks++) {
        float4 mr[8]; float dr[8];
#pragma unroll
        for (int j = 0; j < 8; j++) {
            int k = ks * 32 + q * 8 + j;
            mr[j] = sM[k ^ q];
            dr[j] = sD[k];
        }
#pragma unroll
        for (int mt = 0; mt < 4; mt++) {
            float4 ev = ev4[mt];
            v8s a;
#pragma unroll
            for (int j = 0; j < 8; j++) {
                float xv = fmaxf(dr[j] + ev.x * mr[j].x + ev.y * mr[j].y
                                       + ev.z * mr[j].z + ev.w * mr[j].w, 0.f);
                a[j] = (short)f2bf(xv);
            }
            av[mt][ks] = a;
        }
    }

    // layer 2: MFMA, bias in C-init
    v4f acc[4][4];
#pragma unroll
    for (int nt = 0; nt < 4; nt++) {
        float bb = a2b[nt * 16 + c];
#pragma unroll
        for (int mt = 0; mt < 4; mt++) acc[mt][nt] = (v4f){bb, bb, bb, bb};
    }
#pragma unroll
    for (int nt = 0; nt < 4; nt++) {
#pragma unroll
        for (int ks = 0; ks < 4; ks++) {
            v8s bfr = *(const v8s*)(w2bf + ((size_t)(ks * 4 + nt) * 64 + lane) * 8);
#pragma unroll
            for (int mt = 0; mt < 4; mt++)
                acc[mt][nt] = __builtin_amdgcn_mfma_f32_16x16x32_bf16(av[mt][ks], bfr, acc[mt][nt], 0, 0, 0);
        }
    }

    // layer 3 + sigmoid
    float a3r[4];
#pragma unroll
    for (int nt = 0; nt < 4; nt++) a3r[nt] = a3w[nt * 16 + c];
    float a3b0 = a3b[0];
#pragma unroll
    for (int mt = 0; mt < 4; mt++) {
#pragma unroll
        for (int r = 0; r < 4; r++) {
            float s = 0.f;
#pragma unroll
            for (int nt = 0; nt < 4; nt++) s += fmaxf(acc[mt][nt][r], 0.f) * a3r[nt];
            s += __shfl_xor(s, 1); s += __shfl_xor(s, 2);
            s += __shfl_xor(s, 4); s += __shfl_xor(s, 8);
            if (c == 0) gsh[(wid * 4 + mt) * 16 + q * 4 + r] = 1.f / (1.f + __expf(-(s + a3b0)));
        }
    }
    __syncthreads();

    // per-edge epilogue
    float g = gsh[t];
    float4 evv = sevs[t];
    float v0 = g, v1 = g * evv.x, v2 = g * evv.y, v3 = g * evv.z, v4 = g * evv.w;
#pragma unroll
    for (int d = 32; d > 0; d >>= 1) {
        v0 += __shfl_down(v0, d); v1 += __shfl_down(v1, d); v2 += __shfl_down(v2, d);
        v3 += __shfl_down(v3, d); v4 += __shfl_down(v4, d);
    }
    if (lane == 0) {
        atomicAdd(&sgsum[0], v0); atomicAdd(&sgsum[1], v1); atomicAdd(&sgsum[2], v2);
        atomicAdd(&sgsum[3], v3); atomicAdd(&sgsum[4], v4);
    }
    __syncthreads();
    if (t < 5) atomicAdd(&gsum[t], sgsum[t]);
    int slot = atomicAdd(&pos[my_dst], 1);
    srcv[slot] = my_src;
#pragma unroll
    for (int i4 = 0; i4 < 6; i4++) {
        float4 cc = *(const float4*)(cB + i4 * 4);
        float4 p0 = *(const float4*)(PB + 0 * 24 + i4 * 4);
        float4 p1 = *(const float4*)(PB + 1 * 24 + i4 * 4);
        float4 p2 = *(const float4*)(PB + 2 * 24 + i4 * 4);
        float4 p3 = *(const float4*)(PB + 3 * 24 + i4 * 4);
        float4 o;
        o.x = g * (cc.x + evv.x * p0.x + evv.y * p1.x + evv.z * p2.x + evv.w * p3.x);
        o.y = g * (cc.y + evv.x * p0.y + evv.y * p1.y + evv.z * p2.y + evv.w * p3.y);
        o.z = g * (cc.z + evv.x * p0.z + evv.y * p1.z + evv.z * p2.z + evv.w * p3.z);
        o.w = g * (cc.w + evv.x * p0.w + evv.y * p1.w + evv.z * p2.w + evv.w * p3.w);
        *(float4*)(aleT + (size_t)i4 * Ee * 4 + (size_t)slot * 4) = o;
    }
}

// ---- per-layer agg: single-pass no-max softmax; self-loop handled analytically ----
__global__ __launch_bounds__(256) void k_agg3(
    const int* __restrict__ srcv, const int* __restrict__ seg,
    const float* __restrict__ als, const float* __restrict__ ald,
    const float* __restrict__ aleS_l,
    const unsigned short* __restrict__ hb, unsigned short* __restrict__ aggb,
    const float* __restrict__ gsum, const float* __restrict__ PBl,
    const float* __restrict__ cBl) {
    __shared__ float part[2][512];
    __shared__ float pden[2][4];
    int t = threadIdx.x;
    int lane = t & 63;
    int wv = (t >> 6) & 1;
    int w = t >> 7;
    int n = blockIdx.x * 2 + w;
    int start = seg[n], end = seg[n + 1];
    int deg = end - start;
    int half = (deg + 1) >> 1;
    int s0 = start + wv * half;
    int e0 = wv ? end : start + half;
    int hp = lane >> 4;
    int cch = (lane & 15) * 8;
    float aldh = ald[n * 4 + hp];
    float den = 0.f;
    float4 acc0 = make_float4(0.f, 0.f, 0.f, 0.f);
    float4 acc1 = make_float4(0.f, 0.f, 0.f, 0.f);
    int i = s0;
    for (; i + 4 <= e0; i += 4) {
        int sa = srcv[i], sb = srcv[i + 1], sc = srcv[i + 2], sd = srcv[i + 3];
        float ala = aleS_l[(size_t)(i + 0) * 4 + hp];
        float alb = aleS_l[(size_t)(i + 1) * 4 + hp];
        float alc = aleS_l[(size_t)(i + 2) * 4 + hp];
        float ald_ = aleS_l[(size_t)(i + 3) * 4 + hp];
        float asa = als[sa * 4 + hp], asb = als[sb * 4 + hp];
        float asc = als[sc * 4 + hp], asd = als[sd * 4 + hp];
        uint4 ua = *(const uint4*)(hb + (size_t)sa * 128 + cch);
        uint4 ub = *(const uint4*)(hb + (size_t)sb * 128 + cch);
        uint4 uc = *(const uint4*)(hb + (size_t)sc * 128 + cch);
        uint4 ud = *(const uint4*)(hb + (size_t)sd * 128 + cch);
        float ava = asa + aldh + ala; ava = ava > 0.f ? ava : 0.2f * ava;
        float avb = asb + aldh + alb; avb = avb > 0.f ? avb : 0.2f * avb;
        float avc = asc + aldh + alc; avc = avc > 0.f ? avc : 0.2f * avc;
        float avd = asd + aldh + ald_; avd = avd > 0.f ? avd : 0.2f * avd;
        float ea = __expf(fminf(ava, 60.f));
        float eb = __expf(fminf(avb, 60.f));
        float ec = __expf(fminf(avc, 60.f));
        float ed = __expf(fminf(avd, 60.f));
        den += (ea + eb) + (ec + ed);
        acc0.x += (ea * bflo(ua.x) + eb * bflo(ub.x)) + (ec * bflo(uc.x) + ed * bflo(ud.x));
        acc0.y += (ea * bfhi(ua.x) + eb * bfhi(ub.x)) + (ec * bfhi(uc.x) + ed * bfhi(ud.x));
        acc0.z += (ea * bflo(ua.y) + eb * bflo(ub.y)) + (ec * bflo(uc.y) + ed * bflo(ud.y));
        acc0.w += (ea * bfhi(ua.y) + eb * bfhi(ub.y)) + (ec * bfhi(uc.y) + ed * bfhi(ud.y));
        acc1.x += (ea * bflo(ua.z) + eb * bflo(ub.z)) + (ec * bflo(uc.z) + ed * bflo(ud.z));
        acc1.y += (ea * bfhi(ua.z) + eb * bfhi(ub.z)) + (ec * bfhi(uc.z) + ed * bfhi(ud.z));
        acc1.z += (ea * bflo(ua.w) + eb * bflo(ub.w)) + (ec * bflo(uc.w) + ed * bflo(ud.w));
        acc1.w += (ea * bfhi(ua.w) + eb * bfhi(ub.w)) + (ec * bfhi(uc.w) + ed * bfhi(ud.w));
    }
    for (; i < e0; i++) {
        int sa = srcv[i];
        float ala = aleS_l[(size_t)i * 4 + hp];
        float ava = als[sa * 4 + hp] + aldh + ala;
        ava = ava > 0.f ? ava : 0.2f * ava;
        float ea = __expf(fminf(ava, 60.f));
        den += ea;
        uint4 ua = *(const uint4*)(hb + (size_t)sa * 128 + cch);
        acc0.x += ea * bflo(ua.x); acc0.y += ea * bfhi(ua.x);
        acc0.z += ea * bflo(ua.y); acc0.w += ea * bfhi(ua.y);
        acc1.x += ea * bflo(ua.z); acc1.y += ea * bfhi(ua.z);
        acc1.z += ea * bflo(ua.w); acc1.w += ea * bfhi(ua.w);
    }
    if (wv == 0) {
        // self-loop term: alpha = als[n] + ald[n] + lale_l[hp]
        float lale = (gsum[0] * cBl[hp] + gsum[1] * PBl[hp] + gsum[2] * PBl[24 + hp]
                    + gsum[3] * PBl[48 + hp] + gsum[4] * PBl[72 + hp]) * (1.0f / Ee);
        float av = als[n * 4 + hp] + aldh + lale;
        av = av > 0.f ? av : 0.2f * av;
        float e0 = __expf(fminf(av, 60.f));
        den += e0;
        uint4 ua = *(const uint4*)(hb + (size_t)n * 128 + cch);
        acc0.x += e0 * bflo(ua.x); acc0.y += e0 * bfhi(ua.x);
        acc0.z += e0 * bflo(ua.y); acc0.w += e0 * bfhi(ua.y);
        acc1.x += e0 * bflo(ua.z); acc1.y += e0 * bfhi(ua.z);
        acc1.z += e0 * bflo(ua.w); acc1.w += e0 * bfhi(ua.w);
    }
    if (wv == 1) {
        *(float4*)&part[w][lane * 8] = acc0;
        *(float4*)&part[w][lane * 8 + 4] = acc1;
        if ((lane & 15) == 0) pden[w][hp] = den;
    }
    __syncthreads();
    if (wv == 0) {
        float4 p0 = *(const float4*)&part[w][lane * 8];
        float4 p1 = *(const float4*)&part[w][lane * 8 + 4];
        float inv2 = 1.f / (den + pden[w][hp] + 1e-16f);
        acc0.x = (acc0.x + p0.x) * inv2; acc0.y = (acc0.y + p0.y) * inv2;
        acc0.z = (acc0.z + p0.z) * inv2; acc0.w = (acc0.w + p0.w) * inv2;
        acc1.x = (acc1.x + p1.x) * inv2; acc1.y = (acc1.y + p1.y) * inv2;
        acc1.z = (acc1.z + p1.z) * inv2; acc1.w = (acc1.w + p1.w) * inv2;
        ushort4 q0, q1;
        q0.x = f2bf(acc0.x); q0.y = f2bf(acc0.y); q0.z = f2bf(acc0.z); q0.w = f2bf(acc0.w);
        q1.x = f2bf(acc1.x); q1.y = f2bf(acc1.y); q1.z = f2bf(acc1.z); q1.w = f2bf(acc1.w);
        *(ushort4*)(aggb + (size_t)n * 512 + lane * 8) = q0;
        *(ushort4*)(aggb + (size_t)n * 512 + lane * 8 + 4) = q1;
    }
}

// ---- per-layer: h_new = LN(relu(aggcat @ Wsum + gbias) + h); next-layer als/ald,
//      OR (last layer, owbT != null) fused out = h_new @ ow + ob via MFMA ----
__global__ __launch_bounds__(256) void k_post(
    const unsigned short* __restrict__ aggb, const unsigned short* __restrict__ WsumT_l,
    const float* __restrict__ gbias, const float* __restrict__ lnsc,
    const float* __restrict__ lnbi, float* __restrict__ h,
    unsigned short* __restrict__ hb, const float* __restrict__ Bs_n,
    const float* __restrict__ Bd_n, float* __restrict__ als, float* __restrict__ ald,
    const unsigned short* __restrict__ owbT, const float* __restrict__ ob,
    float* __restrict__ out) {
    int t = threadIdx.x;
    int lane = t & 63, w = t >> 6;
    int n0 = (blockIdx.x * 4 + w) * 16;
    if (n0 >= Nn) return;
    int m = lane & 15, q = lane >> 4;
    v4f acc[8];
#pragma unroll
    for (int nt = 0; nt < 8; nt++) acc[nt] = (v4f){0.f, 0.f, 0.f, 0.f};
    const unsigned short* arow = aggb + (size_t)(n0 + m) * 512 + q * 8;
#pragma unroll 4
    for (int ks = 0; ks < 16; ks++) {
        v8s fa = *(const v8s*)(arow + ks * 32);
#pragma unroll
        for (int nt = 0; nt < 8; nt++) {
            int col = nt * 16 + m;
            v8s fb = *(const v8s*)(WsumT_l + (size_t)col * 512 + ks * 32 + q * 8);
            acc[nt] = __builtin_amdgcn_mfma_f32_16x16x32_bf16(fa, fb, acc[nt], 0, 0, 0);
        }
    }
    float v[8][4];
    float s1[4] = {0.f, 0.f, 0.f, 0.f}, s2[4] = {0.f, 0.f, 0.f, 0.f};
#pragma unroll
    for (int nt = 0; nt < 8; nt++) {
        int col = nt * 16 + m;
        float b = gbias[col];
#pragma unroll
        for (int r = 0; r < 4; r++) {
            int row = n0 + q * 4 + r;
            float val = h[(size_t)row * 128 + col] + fmaxf(acc[nt][r] + b, 0.f);
            v[nt][r] = val;
            s1[r] += val; s2[r] += val * val;
        }
    }
#pragma unroll
    for (int d = 1; d <= 8; d <<= 1) {
#pragma unroll
        for (int r = 0; r < 4; r++) {
            s1[r] += __shfl_xor(s1[r], d);
            s2[r] += __shfl_xor(s2[r], d);
        }
    }
    float o8[8][4];
#pragma unroll
    for (int r = 0; r < 4; r++) {
        float mean = s1[r] * (1.f / 128.f);
        float var = s2[r] * (1.f / 128.f) - mean * mean;
        float rinv = rsqrtf(var + 1e-5f);
        int row = n0 + q * 4 + r;
#pragma unroll
        for (int nt = 0; nt < 8; nt++) {
            int col = nt * 16 + m;
            float o = (v[nt][r] - mean) * rinv * lnsc[col] + lnbi[col];
            o8[nt][r] = o;
            h[(size_t)row * 128 + col] = o;
            hb[(size_t)row * 128 + col] = f2bf(o);
        }
    }
    if (owbT == nullptr) {
        // next-layer als/ald
        float sal[4][4], sad[4][4];
#pragma unroll
        for (int r = 0; r < 4; r++) {
#pragma unroll
            for (int hh = 0; hh < 4; hh++) { sal[r][hh] = 0.f; sad[r][hh] = 0.f; }
        }
#pragma unroll
        for (int nt = 0; nt < 8; nt++) {
            int col = nt * 16 + m;
            float4 bs = *(const float4*)(Bs_n + col * 4);
            float4 bd = *(const float4*)(Bd_n + col * 4);
#pragma unroll
            for (int r = 0; r < 4; r++) {
                float o = o8[nt][r];
                sal[r][0] += o * bs.x; sal[r][1] += o * bs.y;
                sal[r][2] += o * bs.z; sal[r][3] += o * bs.w;
                sad[r][0] += o * bd.x; sad[r][1] += o * bd.y;
                sad[r][2] += o * bd.z; sad[r][3] += o * bd.w;
            }
        }
#pragma unroll
        for (int d = 1; d <= 8; d <<= 1) {
#pragma unroll
            for (int r = 0; r < 4; r++) {
#pragma unroll
                for (int hh = 0; hh < 4; hh++) {
                    sal[r][hh] += __shfl_xor(sal[r][hh], d);
                    sad[r][hh] += __shfl_xor(sad[r][hh], d);
                }
            }
        }
        if (m < 8) {
            int hh = m & 3;
#pragma unroll
            for (int r = 0; r < 4; r++) {
                int row = n0 + q * 4 + r;
                float va = (hh == 0) ? sal[r][0] : (hh == 1) ? sal[r][1] : (hh == 2) ? sal[r][2] : sal[r][3];
                float vd = (hh == 0) ? sad[r][0] : (hh == 1) ? sad[r][1] : (hh == 2) ? sad[r][2] : sad[r][3];
                if (m < 4) als[row * 4 + hh] = va;
                else       ald[row * 4 + hh] = vd;
            }
        }
    } else {
        // fused output projection: out[16 nodes][256] = h_new @ ow + ob
        // A-frags read back from hb (just written by THIS wave's rows)
        v4f oacc[16];
#pragma unroll
        for (int ct = 0; ct < 16; ct++) oacc[ct] = (v4f){0.f, 0.f, 0.f, 0.f};
#pragma unroll
        for (int ks = 0; ks < 4; ks++) {
            v8s fa = *(const v8s*)(hb + (size_t)(n0 + m) * 128 + ks * 32 + q * 8);
#pragma unroll
            for (int ct = 0; ct < 16; ct++) {
                v8s fb = *(const v8s*)(owbT + (size_t)(ct * 16 + m) * 128 + ks * 32 + q * 8);
                oacc[ct] = __builtin_amdgcn_mfma_f32_16x16x32_bf16(fa, fb, oacc[ct], 0, 0, 0);
            }
        }
#pragma unroll
        for (int ct = 0; ct < 16; ct++) {
            float obv = ob[ct * 16 + m];
#pragma unroll
            for (int r = 0; r < 4; r++) {
                int row = n0 + q * 4 + r;
                out[(size_t)row * 256 + ct * 16 + m] = oacc[ct][r] + obv;
            }
        }
    }
}

extern "C" void kernel_launch(void* const* d_in, const int* in_sizes, int n_in,
                              void* d_out, int out_size, void* d_ws, size_t ws_size,
                              hipStream_t stream) {
    const float* x    = (const float*)d_in[0];
    const int*   ei   = (const int*)d_in[1];
    const float* ea   = (const float*)d_in[2];
    const float* vnfc = (const float*)d_in[3];
    const float* nw   = (const float*)d_in[4];
    const float* nb   = (const float*)d_in[5];
    const float* eaw  = (const float*)d_in[6];
    const float* eab  = (const float*)d_in[7];
    const float* vw   = (const float*)d_in[8];
    const float* vb   = (const float*)d_in[9];
    const float* a1w  = (const float*)d_in[10];
    const float* a1b  = (const float*)d_in[11];
    const float* a2w  = (const float*)d_in[12];
    const float* a2b  = (const float*)d_in[13];
    const float* a3w  = (const float*)d_in[14];
    const float* a3b  = (const float*)d_in[15];
    const float* glw  = (const float*)d_in[16];
    const float* gas  = (const float*)d_in[17];
    const float* gad  = (const float*)d_in[18];
    const float* glew = (const float*)d_in[19];
    const float* gae  = (const float*)d_in[20];
    const float* gb   = (const float*)d_in[21];
    const float* lnsc = (const float*)d_in[22];
    const float* lnbi = (const float*)d_in[23];
    const float* ow   = (const float*)d_in[24];
    const float* ob   = (const float*)d_in[25];
    float* out = (float*)d_out;

    char* w = (char*)d_ws;
    size_t o = 0;
    auto allocf = [&](size_t cnt) { float* p = (float*)(w + o); o += ((cnt * 4 + 255) / 256) * 256; return p; };
    auto alloci = [&](size_t cnt) { int* p = (int*)(w + o); o += ((cnt * 4 + 255) / 256) * 256; return p; };
    auto allocu = [&](size_t cnt) { unsigned short* p = (unsigned short*)(w + o); o += ((cnt * 2 + 255) / 256) * 256; return p; };
    // hist + gsum adjacent -> single memset
    int* hist     = alloci(Nn);
    float* gsum   = allocf(8);
    float* h      = allocf((size_t)Nn * 128);
    unsigned short* hb    = allocu((size_t)Nn * 128);
    unsigned short* aggb  = allocu((size_t)Nn * 512);
    unsigned short* WsumT = allocu((size_t)LL * 128 * 512);
    unsigned short* w2bf  = allocu(8192);
    unsigned short* owbT  = allocu(32768);
    float* als    = allocf((size_t)Nn * 4);
    float* ald    = allocf((size_t)Nn * 4);
    float* aleT   = allocf((size_t)LL * Ee * 4);   // dst-sorted slots (real edges only)
    float* Bs     = allocf(3072);
    float* Bd     = allocf(3072);
    float* Be     = allocf(3072);
    float* E1     = allocf(1024);
    float* PB     = allocf(96);
    float* cB     = allocf(24);
    int* seg      = alloci(Nn + 1);
    int* pos      = alloci(Nn);
    int* srcv     = alloci(Ee);

    // one memset covers hist (40000B + pad) and gsum (32B)
    hipMemsetAsync(hist, 0, ((size_t)Nn * 4 + 255) / 256 * 256 + 256, stream);

    k_first<<<7334, 256, 0, stream>>>(x, nw, nb, h, hb, ei, hist,
                                      glw, gas, gad, glew, gae, Bs, Bd, Be,
                                      WsumT, a2w, w2bf, ow, owbT, vnfc, vw, vb, eab,
                                      a1w, a1b, eaw, E1);
    k_scan<<<2, 1024, 0, stream>>>(hist, seg, pos, eaw, eab, Be, PB, cB);
    k_edge<<<938, 256, 0, stream>>>(ea, E1, w2bf, a2b, a3w, a3b, PB, cB,
                                    ei, pos, srcv, aleT, gsum, h, Bs, Bd, als, ald);
    for (int l = 0; l < LL; l++) {
        int ln = (l + 1) % LL;
        k_agg3<<<Nn / 2, 256, 0, stream>>>(srcv, seg, als, ald,
                                           aleT + (size_t)l * Ee * 4, hb, aggb,
                                           gsum, PB + l * 4, cB + l * 4);
        k_post<<<(625 + 3) / 4, 256, 0, stream>>>(aggb, WsumT + (size_t)l * 65536,
                                                  gb + l * 128, lnsc + l * 128, lnbi + l * 128,
                                                  h, hb, Bs + ln * 512, Bd + ln * 512, als, ald,
                                                  (l == LL - 1) ? owbT : (const unsigned short*)nullptr,
                                                  ob, out);
    }
}